// Round 1
// baseline (591.488 us; speedup 1.0000x reference)
//
#include <hip/hip_runtime.h>
#include <math.h>

#define N_SEQ 512
#define DIM   1024
#define HEADS 16
#define DH    64
#define P     32
#define P2    16
#define O3    3072   // 3 * HEADS * DH

// ---------------------------------------------------------------------------
// Generic fp32 NT GEMM: C[m,n] = sum_k A[m*K+k] * B[n*K+k]
// Block: 256 threads (16x16), tile TM=16*WM x TN=16*WN, K-tile 16.
// M % TM == 0, N % TN == 0, K % 16 == 0 assumed.
// ---------------------------------------------------------------------------
template<int WM, int WN>
__global__ __launch_bounds__(256) void gemm_nt(const float* __restrict__ A,
                                               const float* __restrict__ B,
                                               float* __restrict__ C,
                                               int M, int N, int K) {
  constexpr int TM = 16 * WM;
  constexpr int TN = 16 * WN;
  constexpr int TK = 16;
  __shared__ __align__(16) float As[TK][TM + 4];
  __shared__ __align__(16) float Bs[TK][TN + 4];

  const int tid = threadIdx.x;
  const int bm = blockIdx.x * TM;
  const int bn = blockIdx.y * TN;
  const int tx = tid & 15;
  const int ty = tid >> 4;

  float acc[WM][WN];
#pragma unroll
  for (int i = 0; i < WM; ++i)
#pragma unroll
    for (int j = 0; j < WN; ++j) acc[i][j] = 0.f;

  const int lc = tid & (TK - 1);   // k-col within tile
  const int lr = tid / TK;         // starting row, step 16

  for (int k0 = 0; k0 < K; k0 += TK) {
#pragma unroll
    for (int r = lr; r < TM; r += 256 / TK)
      As[lc][r] = A[(size_t)(bm + r) * K + k0 + lc];
#pragma unroll
    for (int r = lr; r < TN; r += 256 / TK)
      Bs[lc][r] = B[(size_t)(bn + r) * K + k0 + lc];
    __syncthreads();

#pragma unroll
    for (int kk = 0; kk < TK; ++kk) {
      float av[WM], bv[WN];
#pragma unroll
      for (int i = 0; i < WM; ++i) av[i] = As[kk][ty * WM + i];
#pragma unroll
      for (int j = 0; j < WN; ++j) bv[j] = Bs[kk][tx * WN + j];
#pragma unroll
      for (int i = 0; i < WM; ++i)
#pragma unroll
        for (int j = 0; j < WN; ++j) acc[i][j] += av[i] * bv[j];
    }
    __syncthreads();
  }

#pragma unroll
  for (int i = 0; i < WM; ++i)
#pragma unroll
    for (int j = 0; j < WN; ++j)
      C[(size_t)(bm + ty * WM + i) * N + bn + tx * WN + j] = acc[i][j];
}

// ---------------------------------------------------------------------------
// Fused per-position projections:
//   q[h,d] = qkv[n, d*48 + h], k[h,d] = qkv[n, d*48+16+h], v[h,d] = qkv[n, d*48+32+h]
//   qp[h,p] = sum_d q[h,d]*Wq[p,d] + bq[p]   (kp similarly with Wk,bk)
//   a[h,n,q] = sum_p qp[h,p]*W1[q,p]      (W1q = W1[:, :32])
//   c[h,n,q] = sum_p kp[h,p]*W1[q,32+p]   (W1k = W1[:, 32:])
//   v stored as v[h,n,d]
// One block per n (512 blocks, 256 threads).
// ---------------------------------------------------------------------------
__global__ __launch_bounds__(256) void proj_kernel(
    const float* __restrict__ qkv,
    const float* __restrict__ Wq, const float* __restrict__ bq,
    const float* __restrict__ Wk, const float* __restrict__ bk,
    const float* __restrict__ W1,
    float* __restrict__ a_out, float* __restrict__ c_out,
    float* __restrict__ v_out) {
  const int n = blockIdx.x;
  const int tid = threadIdx.x;
  __shared__ float row[O3];
  __shared__ float qp_s[HEADS][P];
  __shared__ float kp_s[HEADS][P];

  for (int t = tid; t < O3; t += 256) row[t] = qkv[(size_t)n * O3 + t];
  __syncthreads();

  for (int t = tid; t < HEADS * P; t += 256) {
    const int h = t >> 5, p = t & 31;
    float sq = bq[p], sk = bk[p];
#pragma unroll
    for (int d = 0; d < DH; ++d) {
      sq += row[d * 48 + h] * Wq[p * DH + d];
      sk += row[d * 48 + 16 + h] * Wk[p * DH + d];
    }
    qp_s[h][p] = sq;
    kp_s[h][p] = sk;
  }
  __syncthreads();

  for (int t = tid; t < HEADS * P; t += 256) {
    const int h = t >> 5, qq = t & 31;
    float sa = 0.f, sc2 = 0.f;
#pragma unroll
    for (int p = 0; p < P; ++p) {
      sa  += qp_s[h][p] * W1[qq * (2 * P) + p];
      sc2 += kp_s[h][p] * W1[qq * (2 * P) + P + p];
    }
    a_out[((size_t)h * N_SEQ + n) * P + qq] = sa;
    c_out[((size_t)h * N_SEQ + n) * P + qq] = sc2;
  }

  for (int t = tid; t < HEADS * DH; t += 256) {
    const int h = t >> 6, d = t & 63;
    v_out[((size_t)h * N_SEQ + n) * DH + d] = row[d * 48 + 32 + h];
  }
}

// ---------------------------------------------------------------------------
// Per (h, i) row: MLP scores over j, causal softmax, attn @ V.
// 256 threads; each thread handles j = tid and j = tid + 256.
// attnout layout: [i, h*DH + d]  (ready for the output GEMM).
// ---------------------------------------------------------------------------
__global__ __launch_bounds__(256) void attn_kernel(
    const float* __restrict__ a_g, const float* __restrict__ c_g,
    const float* __restrict__ v_g, const float* __restrict__ b1,
    const float* __restrict__ W2, const float* __restrict__ b2,
    const float* __restrict__ W3, const float* __restrict__ b3,
    float* __restrict__ attnout) {
  const int i = blockIdx.x;
  const int h = blockIdx.y;
  const int tid = threadIdx.x;

  __shared__ __align__(16) float a_s[P];
  __shared__ __align__(16) float b1_s[P];
  __shared__ __align__(16) float W2_s[P2 * P];
  __shared__ float b2_s[P2], W3_s[P2];
  __shared__ float sc[N_SEQ];
  __shared__ float red[256];

  if (tid < P) {
    a_s[tid]  = a_g[((size_t)h * N_SEQ + i) * P + tid];
    b1_s[tid] = b1[tid];
  }
  if (tid >= 32 && tid < 48) {
    b2_s[tid - 32] = b2[tid - 32];
    W3_s[tid - 32] = W3[tid - 32];
  }
  for (int t = tid; t < P2 * P; t += 256) W2_s[t] = W2[t];
  __syncthreads();

  const float b3v = b3[0];
  const int j0 = tid, j1 = tid + 256;

  float h1a[P], h1b[P];
  {
    const float4* c0 = (const float4*)(c_g + ((size_t)h * N_SEQ + j0) * P);
    const float4* c1 = (const float4*)(c_g + ((size_t)h * N_SEQ + j1) * P);
#pragma unroll
    for (int pp = 0; pp < 8; ++pp) {
      const float4 cv0 = c0[pp];
      const float4 cv1 = c1[pp];
      h1a[4 * pp + 0] = fmaxf(a_s[4 * pp + 0] + cv0.x + b1_s[4 * pp + 0], 0.f);
      h1a[4 * pp + 1] = fmaxf(a_s[4 * pp + 1] + cv0.y + b1_s[4 * pp + 1], 0.f);
      h1a[4 * pp + 2] = fmaxf(a_s[4 * pp + 2] + cv0.z + b1_s[4 * pp + 2], 0.f);
      h1a[4 * pp + 3] = fmaxf(a_s[4 * pp + 3] + cv0.w + b1_s[4 * pp + 3], 0.f);
      h1b[4 * pp + 0] = fmaxf(a_s[4 * pp + 0] + cv1.x + b1_s[4 * pp + 0], 0.f);
      h1b[4 * pp + 1] = fmaxf(a_s[4 * pp + 1] + cv1.y + b1_s[4 * pp + 1], 0.f);
      h1b[4 * pp + 2] = fmaxf(a_s[4 * pp + 2] + cv1.z + b1_s[4 * pp + 2], 0.f);
      h1b[4 * pp + 3] = fmaxf(a_s[4 * pp + 3] + cv1.w + b1_s[4 * pp + 3], 0.f);
    }
  }

  float s0 = b3v, s1 = b3v;
  const float4* W2v = (const float4*)W2_s;
#pragma unroll
  for (int q = 0; q < P2; ++q) {
    float acc0 = b2_s[q], acc1 = acc0;
#pragma unroll
    for (int pp = 0; pp < 8; ++pp) {
      const float4 w = W2v[q * 8 + pp];
      acc0 += w.x * h1a[4 * pp + 0] + w.y * h1a[4 * pp + 1] +
              w.z * h1a[4 * pp + 2] + w.w * h1a[4 * pp + 3];
      acc1 += w.x * h1b[4 * pp + 0] + w.y * h1b[4 * pp + 1] +
              w.z * h1b[4 * pp + 2] + w.w * h1b[4 * pp + 3];
    }
    s0 += W3_s[q] * fmaxf(acc0, 0.f);
    s1 += W3_s[q] * fmaxf(acc1, 0.f);
  }

  const bool act0 = (j0 <= i), act1 = (j1 <= i);

  // --- max reduce ---
  float lm = -1e30f;
  if (act0) lm = s0;
  if (act1) lm = fmaxf(lm, s1);
  red[tid] = lm;
  __syncthreads();
  for (int sft = 128; sft > 0; sft >>= 1) {
    if (tid < sft) red[tid] = fmaxf(red[tid], red[tid + sft]);
    __syncthreads();
  }
  const float rmax = red[0];
  __syncthreads();

  // --- exp + sum reduce ---
  const float e0 = act0 ? __expf(s0 - rmax) : 0.f;
  const float e1 = act1 ? __expf(s1 - rmax) : 0.f;
  sc[j0] = e0;
  sc[j1] = e1;
  red[tid] = e0 + e1;
  __syncthreads();
  for (int sft = 128; sft > 0; sft >>= 1) {
    if (tid < sft) red[tid] += red[tid + sft];
    __syncthreads();
  }
  const float inv = 1.f / red[0];
  __syncthreads();

  // --- attn @ V ---
  const int d = tid & 63, g = tid >> 6;
  float accv = 0.f;
  for (int j = g; j <= i; j += 4)
    accv += sc[j] * v_g[((size_t)h * N_SEQ + j) * DH + d];
  red[tid] = accv;
  __syncthreads();
  if (tid < 64) {
    const float r = red[tid] + red[tid + 64] + red[tid + 128] + red[tid + 192];
    attnout[(size_t)i * DIM + h * DH + tid] = r * inv;
  }
}

// ---------------------------------------------------------------------------
extern "C" void kernel_launch(void* const* d_in, const int* in_sizes, int n_in,
                              void* d_out, int out_size, void* d_ws, size_t ws_size,
                              hipStream_t stream) {
  const float* x    = (const float*)d_in[0];
  const float* Wqkv = (const float*)d_in[1];
  const float* Wout = (const float*)d_in[2];
  const float* Wq   = (const float*)d_in[3];
  const float* bq   = (const float*)d_in[4];
  const float* Wk   = (const float*)d_in[5];
  const float* bk   = (const float*)d_in[6];
  const float* W1   = (const float*)d_in[7];
  const float* b1   = (const float*)d_in[8];
  const float* W2   = (const float*)d_in[9];
  const float* b2   = (const float*)d_in[10];
  const float* W3   = (const float*)d_in[11];
  const float* b3   = (const float*)d_in[12];
  float* out = (float*)d_out;

  float* ws      = (float*)d_ws;
  float* qkv     = ws;                                  // 512*3072
  float* a_buf   = qkv + (size_t)N_SEQ * O3;            // 16*512*32
  float* c_buf   = a_buf + (size_t)HEADS * N_SEQ * P;   // 16*512*32
  float* v_buf   = c_buf + (size_t)HEADS * N_SEQ * P;   // 16*512*64
  float* attnout = v_buf + (size_t)HEADS * N_SEQ * DH;  // 512*1024

  // 1) QKV GEMM: (512 x 3072) = x(512x1024) @ Wqkv^T
  dim3 g1(N_SEQ / 128, O3 / 64);
  gemm_nt<8, 4><<<g1, 256, 0, stream>>>(x, Wqkv, qkv, N_SEQ, O3, DIM);

  // 2) per-position projections -> a, c, v
  proj_kernel<<<N_SEQ, 256, 0, stream>>>(qkv, Wq, bq, Wk, bk, W1,
                                         a_buf, c_buf, v_buf);

  // 3) MLP scores + causal softmax + attn@V
  dim3 g3(N_SEQ, HEADS);
  attn_kernel<<<g3, 256, 0, stream>>>(a_buf, c_buf, v_buf, b1, W2, b2, W3, b3,
                                      attnout);

  // 4) output GEMM: (512 x 1024) = attnout(512x1024) @ Wout^T
  dim3 g4(N_SEQ / 64, DIM / 64);
  gemm_nt<4, 4><<<g4, 256, 0, stream>>>(attnout, Wout, out, N_SEQ, DIM, DIM);
}

// Round 2
// 339.744 us; speedup vs baseline: 1.7410x; 1.7410x over previous
//
#include <hip/hip_runtime.h>
#include <math.h>

#define N_SEQ 512
#define DIM   1024
#define HEADS 16
#define DH    64
#define P     32
#define P2    16
#define O3    3072   // 3 * HEADS * DH

typedef short bf16x8 __attribute__((ext_vector_type(8)));
typedef float f32x4  __attribute__((ext_vector_type(4)));

// ---------------------------------------------------------------------------
// fp32 -> bf16 (RNE) for three arrays in one launch. Counts are in float4s.
// ---------------------------------------------------------------------------
__device__ inline unsigned short f2bf(float f) {
  union { float f; unsigned u; } v; v.f = f;
  unsigned r = (v.u + 0x7fffu + ((v.u >> 16) & 1u)) >> 16;
  return (unsigned short)r;
}

__global__ __launch_bounds__(256) void cvt3_bf16(
    const float4* __restrict__ s0, ushort4* __restrict__ d0, int n0,
    const float4* __restrict__ s1, ushort4* __restrict__ d1, int n1,
    const float4* __restrict__ s2, ushort4* __restrict__ d2, int n2) {
  const int total = n0 + n1 + n2;
  for (int t = blockIdx.x * 256 + threadIdx.x; t < total;
       t += gridDim.x * 256) {
    const float4* s; ushort4* d; int off;
    if (t < n0)            { s = s0; d = d0; off = t; }
    else if (t < n0 + n1)  { s = s1; d = d1; off = t - n0; }
    else                   { s = s2; d = d2; off = t - n0 - n1; }
    const float4 v = s[off];
    ushort4 o;
    o.x = f2bf(v.x); o.y = f2bf(v.y); o.z = f2bf(v.z); o.w = f2bf(v.w);
    d[off] = o;
  }
}

// ---------------------------------------------------------------------------
// bf16 MFMA NT GEMM: C[m,n] = sum_k A[m,k]*B[n,k], A:MxK bf16, B:NxK bf16,
// C fp32. One 16x16 tile per wave, K%32==0, M%16==0, N%16==0.
// A-frag: lane holds A[m=lane&15][k0 + (lane>>4)*8 + j], j=0..7 (16B load).
// B-frag: lane holds B[n=lane&15][same k] (= B^T column segment).
// D: lane l, reg r -> C[(l>>4)*4 + r][l&15]   [verified layout, m89/m91]
// ---------------------------------------------------------------------------
__global__ __launch_bounds__(256) void gemm_mfma_nt(
    const short* __restrict__ A, const short* __restrict__ B,
    float* __restrict__ C, int M, int N, int K) {
  const int tilesN = N >> 4;
  const int wave = blockIdx.x * 4 + (threadIdx.x >> 6);
  const int tm = wave / tilesN;
  const int tn = wave % tilesN;
  if (tm >= (M >> 4)) return;

  const int lane = threadIdx.x & 63;
  const int m = lane & 15;
  const int quad = lane >> 4;

  const short* pa = A + (size_t)(tm * 16 + m) * K + quad * 8;
  const short* pb = B + (size_t)(tn * 16 + m) * K + quad * 8;

  f32x4 acc = {0.f, 0.f, 0.f, 0.f};
#pragma unroll 4
  for (int k = 0; k < K; k += 32) {
    const bf16x8 av = *(const bf16x8*)(pa + k);
    const bf16x8 bv = *(const bf16x8*)(pb + k);
    acc = __builtin_amdgcn_mfma_f32_16x16x32_bf16(av, bv, acc, 0, 0, 0);
  }

  float* pc = C + (size_t)(tm * 16 + quad * 4) * N + tn * 16 + m;
#pragma unroll
  for (int r = 0; r < 4; ++r) pc[(size_t)r * N] = acc[r];
}

// ---------------------------------------------------------------------------
// Fused per-position projections (unchanged from round 0).
// ---------------------------------------------------------------------------
__global__ __launch_bounds__(256) void proj_kernel(
    const float* __restrict__ qkv,
    const float* __restrict__ Wq, const float* __restrict__ bq,
    const float* __restrict__ Wk, const float* __restrict__ bk,
    const float* __restrict__ W1,
    float* __restrict__ a_out, float* __restrict__ c_out,
    float* __restrict__ v_out) {
  const int n = blockIdx.x;
  const int tid = threadIdx.x;
  __shared__ float row[O3];
  __shared__ float qp_s[HEADS][P];
  __shared__ float kp_s[HEADS][P];

  for (int t = tid; t < O3; t += 256) row[t] = qkv[(size_t)n * O3 + t];
  __syncthreads();

  for (int t = tid; t < HEADS * P; t += 256) {
    const int h = t >> 5, p = t & 31;
    float sq = bq[p], sk = bk[p];
#pragma unroll
    for (int d = 0; d < DH; ++d) {
      sq += row[d * 48 + h] * Wq[p * DH + d];
      sk += row[d * 48 + 16 + h] * Wk[p * DH + d];
    }
    qp_s[h][p] = sq;
    kp_s[h][p] = sk;
  }
  __syncthreads();

  for (int t = tid; t < HEADS * P; t += 256) {
    const int h = t >> 5, qq = t & 31;
    float sa = 0.f, sc2 = 0.f;
#pragma unroll
    for (int p = 0; p < P; ++p) {
      sa  += qp_s[h][p] * W1[qq * (2 * P) + p];
      sc2 += kp_s[h][p] * W1[qq * (2 * P) + P + p];
    }
    a_out[((size_t)h * N_SEQ + n) * P + qq] = sa;
    c_out[((size_t)h * N_SEQ + n) * P + qq] = sc2;
  }

  for (int t = tid; t < HEADS * DH; t += 256) {
    const int h = t >> 6, d = t & 63;
    v_out[((size_t)h * N_SEQ + n) * DH + d] = row[d * 48 + 32 + h];
  }
}

// ---------------------------------------------------------------------------
// Per (h, i): MLP scores over j, causal softmax, attn @ V.
// Now writes attnout in bf16 (feeds the bf16 output GEMM).
// ---------------------------------------------------------------------------
__global__ __launch_bounds__(256) void attn_kernel(
    const float* __restrict__ a_g, const float* __restrict__ c_g,
    const float* __restrict__ v_g, const float* __restrict__ b1,
    const float* __restrict__ W2, const float* __restrict__ b2,
    const float* __restrict__ W3, const float* __restrict__ b3,
    short* __restrict__ attnout) {
  const int i = blockIdx.x;
  const int h = blockIdx.y;
  const int tid = threadIdx.x;

  __shared__ __align__(16) float a_s[P];
  __shared__ __align__(16) float b1_s[P];
  __shared__ __align__(16) float W2_s[P2 * P];
  __shared__ float b2_s[P2], W3_s[P2];
  __shared__ float sc[N_SEQ];
  __shared__ float red[256];

  if (tid < P) {
    a_s[tid]  = a_g[((size_t)h * N_SEQ + i) * P + tid];
    b1_s[tid] = b1[tid];
  }
  if (tid >= 32 && tid < 48) {
    b2_s[tid - 32] = b2[tid - 32];
    W3_s[tid - 32] = W3[tid - 32];
  }
  for (int t = tid; t < P2 * P; t += 256) W2_s[t] = W2[t];
  __syncthreads();

  const float b3v = b3[0];
  const int j0 = tid, j1 = tid + 256;

  float h1a[P], h1b[P];
  {
    const float4* c0 = (const float4*)(c_g + ((size_t)h * N_SEQ + j0) * P);
    const float4* c1 = (const float4*)(c_g + ((size_t)h * N_SEQ + j1) * P);
#pragma unroll
    for (int pp = 0; pp < 8; ++pp) {
      const float4 cv0 = c0[pp];
      const float4 cv1 = c1[pp];
      h1a[4 * pp + 0] = fmaxf(a_s[4 * pp + 0] + cv0.x + b1_s[4 * pp + 0], 0.f);
      h1a[4 * pp + 1] = fmaxf(a_s[4 * pp + 1] + cv0.y + b1_s[4 * pp + 1], 0.f);
      h1a[4 * pp + 2] = fmaxf(a_s[4 * pp + 2] + cv0.z + b1_s[4 * pp + 2], 0.f);
      h1a[4 * pp + 3] = fmaxf(a_s[4 * pp + 3] + cv0.w + b1_s[4 * pp + 3], 0.f);
      h1b[4 * pp + 0] = fmaxf(a_s[4 * pp + 0] + cv1.x + b1_s[4 * pp + 0], 0.f);
      h1b[4 * pp + 1] = fmaxf(a_s[4 * pp + 1] + cv1.y + b1_s[4 * pp + 1], 0.f);
      h1b[4 * pp + 2] = fmaxf(a_s[4 * pp + 2] + cv1.z + b1_s[4 * pp + 2], 0.f);
      h1b[4 * pp + 3] = fmaxf(a_s[4 * pp + 3] + cv1.w + b1_s[4 * pp + 3], 0.f);
    }
  }

  float s0 = b3v, s1 = b3v;
  const float4* W2v = (const float4*)W2_s;
#pragma unroll
  for (int q = 0; q < P2; ++q) {
    float acc0 = b2_s[q], acc1 = acc0;
#pragma unroll
    for (int pp = 0; pp < 8; ++pp) {
      const float4 w = W2v[q * 8 + pp];
      acc0 += w.x * h1a[4 * pp + 0] + w.y * h1a[4 * pp + 1] +
              w.z * h1a[4 * pp + 2] + w.w * h1a[4 * pp + 3];
      acc1 += w.x * h1b[4 * pp + 0] + w.y * h1b[4 * pp + 1] +
              w.z * h1b[4 * pp + 2] + w.w * h1b[4 * pp + 3];
    }
    s0 += W3_s[q] * fmaxf(acc0, 0.f);
    s1 += W3_s[q] * fmaxf(acc1, 0.f);
  }

  const bool act0 = (j0 <= i), act1 = (j1 <= i);

  float lm = -1e30f;
  if (act0) lm = s0;
  if (act1) lm = fmaxf(lm, s1);
  red[tid] = lm;
  __syncthreads();
  for (int sft = 128; sft > 0; sft >>= 1) {
    if (tid < sft) red[tid] = fmaxf(red[tid], red[tid + sft]);
    __syncthreads();
  }
  const float rmax = red[0];
  __syncthreads();

  const float e0 = act0 ? __expf(s0 - rmax) : 0.f;
  const float e1 = act1 ? __expf(s1 - rmax) : 0.f;
  sc[j0] = e0;
  sc[j1] = e1;
  red[tid] = e0 + e1;
  __syncthreads();
  for (int sft = 128; sft > 0; sft >>= 1) {
    if (tid < sft) red[tid] += red[tid + sft];
    __syncthreads();
  }
  const float inv = 1.f / red[0];
  __syncthreads();

  const int d = tid & 63, g = tid >> 6;
  float accv = 0.f;
  for (int j = g; j <= i; j += 4)
    accv += sc[j] * v_g[((size_t)h * N_SEQ + j) * DH + d];
  red[tid] = accv;
  __syncthreads();
  if (tid < 64) {
    const float r = red[tid] + red[tid + 64] + red[tid + 128] + red[tid + 192];
    attnout[(size_t)i * DIM + h * DH + tid] = (short)f2bf(r * inv);
  }
}

// ---------------------------------------------------------------------------
extern "C" void kernel_launch(void* const* d_in, const int* in_sizes, int n_in,
                              void* d_out, int out_size, void* d_ws, size_t ws_size,
                              hipStream_t stream) {
  const float* x    = (const float*)d_in[0];
  const float* Wqkv = (const float*)d_in[1];
  const float* Wout = (const float*)d_in[2];
  const float* Wq   = (const float*)d_in[3];
  const float* bq   = (const float*)d_in[4];
  const float* Wk   = (const float*)d_in[5];
  const float* bk   = (const float*)d_in[6];
  const float* W1   = (const float*)d_in[7];
  const float* b1   = (const float*)d_in[8];
  const float* W2   = (const float*)d_in[9];
  const float* b2   = (const float*)d_in[10];
  const float* W3   = (const float*)d_in[11];
  const float* b3   = (const float*)d_in[12];
  float* out = (float*)d_out;

  float* ws      = (float*)d_ws;
  float* qkv     = ws;                                   // 512*3072 f32
  float* a_buf   = qkv + (size_t)N_SEQ * O3;             // 16*512*32 f32
  float* c_buf   = a_buf + (size_t)HEADS * N_SEQ * P;    // 16*512*32 f32
  float* v_buf   = c_buf + (size_t)HEADS * N_SEQ * P;    // 16*512*64 f32
  short* xb      = (short*)(v_buf + (size_t)HEADS * N_SEQ * DH);
  short* Wqkvb   = xb + (size_t)N_SEQ * DIM;             // 3072*1024 bf16
  short* Woutb   = Wqkvb + (size_t)O3 * DIM;             // 1024*1024 bf16
  short* attnb   = Woutb + (size_t)DIM * DIM;            // 512*1024 bf16

  // 0) convert x, Wqkv, Wout to bf16
  const int n0 = (N_SEQ * DIM) / 4;       // float4 counts
  const int n1 = (O3 * DIM) / 4;
  const int n2 = (DIM * DIM) / 4;
  const int totalv = n0 + n1 + n2;
  cvt3_bf16<<<(totalv + 255) / 256, 256, 0, stream>>>(
      (const float4*)x,    (ushort4*)xb,    n0,
      (const float4*)Wqkv, (ushort4*)Wqkvb, n1,
      (const float4*)Wout, (ushort4*)Woutb, n2);

  // 1) QKV GEMM (bf16 mfma): qkv[n,o] = sum_c x[n,c]*Wqkv[o,c]
  {
    const int waves = (N_SEQ / 16) * (O3 / 16);   // 6144
    gemm_mfma_nt<<<waves / 4, 256, 0, stream>>>(xb, Wqkvb, qkv,
                                                N_SEQ, O3, DIM);
  }

  // 2) per-position projections -> a, c, v
  proj_kernel<<<N_SEQ, 256, 0, stream>>>(qkv, Wq, bq, Wk, bk, W1,
                                         a_buf, c_buf, v_buf);

  // 3) MLP scores + causal softmax + attn@V (writes bf16 attnout)
  dim3 g3(N_SEQ, HEADS);
  attn_kernel<<<g3, 256, 0, stream>>>(a_buf, c_buf, v_buf, b1, W2, b2, W3, b3,
                                      attnb);

  // 4) output GEMM (bf16 mfma): out[n,o] = sum_e attnout[n,e]*Wout[o,e]
  {
    const int waves = (N_SEQ / 16) * (DIM / 16);  // 2048
    gemm_mfma_nt<<<waves / 4, 256, 0, stream>>>(attnb, Woutb, out,
                                                N_SEQ, DIM, DIM);
  }
}

// Round 3
// 255.632 us; speedup vs baseline: 2.3138x; 1.3290x over previous
//
#include <hip/hip_runtime.h>
#include <hip/hip_bf16.h>
#include <math.h>

#define N_SEQ 512
#define DIM   1024
#define HEADS 16
#define DH    64
#define P     32
#define P2    16
#define O3    3072   // 3 * HEADS * DH

typedef short bf16x8 __attribute__((ext_vector_type(8)));
typedef float f32x4  __attribute__((ext_vector_type(4)));

__device__ inline unsigned short f2bf(float f) {
  union { float f; unsigned u; } v; v.f = f;
  unsigned r = (v.u + 0x7fffu + ((v.u >> 16) & 1u)) >> 16;
  return (unsigned short)r;
}

// ---------------------------------------------------------------------------
// fp32 -> bf16 (RNE) for three arrays in one launch. Counts in float4s.
// ---------------------------------------------------------------------------
__global__ __launch_bounds__(256) void cvt3_bf16(
    const float4* __restrict__ s0, ushort4* __restrict__ d0, int n0,
    const float4* __restrict__ s1, ushort4* __restrict__ d1, int n1,
    const float4* __restrict__ s2, ushort4* __restrict__ d2, int n2) {
  const int total = n0 + n1 + n2;
  for (int t = blockIdx.x * 256 + threadIdx.x; t < total;
       t += gridDim.x * 256) {
    const float4* s; ushort4* d; int off;
    if (t < n0)            { s = s0; d = d0; off = t; }
    else if (t < n0 + n1)  { s = s1; d = d1; off = t - n0; }
    else                   { s = s2; d = d2; off = t - n0 - n1; }
    const float4 v = s[off];
    ushort4 o;
    o.x = f2bf(v.x); o.y = f2bf(v.y); o.z = f2bf(v.z); o.w = f2bf(v.w);
    d[off] = o;
  }
}

// ---------------------------------------------------------------------------
// bf16 MFMA NT GEMM, 2x2 16-tiles per wave (32x32 out/wave).
// C[m,n] = sum_k A[m,k]*B[n,k]. K%32==0, M%32==0, N%32==0.
// ---------------------------------------------------------------------------
__global__ __launch_bounds__(256) void gemm_mfma_nt2(
    const short* __restrict__ A, const short* __restrict__ B,
    float* __restrict__ C, int M, int N, int K) {
  const int tilesN = N >> 5;
  const int wave = blockIdx.x * 4 + (threadIdx.x >> 6);
  const int tm = wave / tilesN;
  const int tn = wave % tilesN;
  if (tm >= (M >> 5)) return;

  const int lane = threadIdx.x & 63;
  const int m = lane & 15;
  const int quad = lane >> 4;

  const short* pa0 = A + (size_t)(tm * 32 + m) * K + quad * 8;
  const short* pa1 = pa0 + (size_t)16 * K;
  const short* pb0 = B + (size_t)(tn * 32 + m) * K + quad * 8;
  const short* pb1 = pb0 + (size_t)16 * K;

  f32x4 acc00 = {0.f,0.f,0.f,0.f}, acc01 = {0.f,0.f,0.f,0.f};
  f32x4 acc10 = {0.f,0.f,0.f,0.f}, acc11 = {0.f,0.f,0.f,0.f};
#pragma unroll 4
  for (int k = 0; k < K; k += 32) {
    const bf16x8 a0 = *(const bf16x8*)(pa0 + k);
    const bf16x8 a1 = *(const bf16x8*)(pa1 + k);
    const bf16x8 b0 = *(const bf16x8*)(pb0 + k);
    const bf16x8 b1 = *(const bf16x8*)(pb1 + k);
    acc00 = __builtin_amdgcn_mfma_f32_16x16x32_bf16(a0, b0, acc00, 0, 0, 0);
    acc01 = __builtin_amdgcn_mfma_f32_16x16x32_bf16(a0, b1, acc01, 0, 0, 0);
    acc10 = __builtin_amdgcn_mfma_f32_16x16x32_bf16(a1, b0, acc10, 0, 0, 0);
    acc11 = __builtin_amdgcn_mfma_f32_16x16x32_bf16(a1, b1, acc11, 0, 0, 0);
  }

  // D: lane l, reg r -> C[tile_m + (l>>4)*4 + r][tile_n + (l&15)]
  float* pc00 = C + (size_t)(tm * 32 + quad * 4) * N + tn * 32 + m;
#pragma unroll
  for (int r = 0; r < 4; ++r) {
    pc00[(size_t)r * N]            = acc00[r];
    pc00[(size_t)r * N + 16]       = acc01[r];
    pc00[(size_t)(r + 16) * N]      = acc10[r];
    pc00[(size_t)(r + 16) * N + 16] = acc11[r];
  }
}

// ---------------------------------------------------------------------------
// Fused per-position projections (unchanged).
// ---------------------------------------------------------------------------
__global__ __launch_bounds__(256) void proj_kernel(
    const float* __restrict__ qkv,
    const float* __restrict__ Wq, const float* __restrict__ bq,
    const float* __restrict__ Wk, const float* __restrict__ bk,
    const float* __restrict__ W1,
    float* __restrict__ a_out, float* __restrict__ c_out,
    float* __restrict__ v_out) {
  const int n = blockIdx.x;
  const int tid = threadIdx.x;
  __shared__ float row[O3];
  __shared__ float qp_s[HEADS][P];
  __shared__ float kp_s[HEADS][P];

  for (int t = tid; t < O3; t += 256) row[t] = qkv[(size_t)n * O3 + t];
  __syncthreads();

  for (int t = tid; t < HEADS * P; t += 256) {
    const int h = t >> 5, p = t & 31;
    float sq = bq[p], sk = bk[p];
#pragma unroll
    for (int d = 0; d < DH; ++d) {
      sq += row[d * 48 + h] * Wq[p * DH + d];
      sk += row[d * 48 + 16 + h] * Wk[p * DH + d];
    }
    qp_s[h][p] = sq;
    kp_s[h][p] = sk;
  }
  __syncthreads();

  for (int t = tid; t < HEADS * P; t += 256) {
    const int h = t >> 5, qq = t & 31;
    float sa = 0.f, sc2 = 0.f;
#pragma unroll
    for (int p = 0; p < P; ++p) {
      sa  += qp_s[h][p] * W1[qq * (2 * P) + p];
      sc2 += kp_s[h][p] * W1[qq * (2 * P) + P + p];
    }
    a_out[((size_t)h * N_SEQ + n) * P + qq] = sa;
    c_out[((size_t)h * N_SEQ + n) * P + qq] = sc2;
  }

  for (int t = tid; t < HEADS * DH; t += 256) {
    const int h = t >> 6, d = t & 63;
    v_out[((size_t)h * N_SEQ + n) * DH + d] = row[d * 48 + 32 + h];
  }
}

// ---------------------------------------------------------------------------
// Per (h, i): MFMA-based MLP scores over causal j-tiles, softmax, attn@V.
//   Per 16-j tile one mfma_f32_16x16x32_bf16:
//     A[j=lane&15][p=quad*8+jj] = bf16(relu(a_i[p]+c_j[p]+b1[p]))
//     B[q=lane&15][p]           = bf16(W2[q][p])
//     D[j=quad*4+r][q=lane&15]  -> +b2, relu, *W3, butterfly-sum over q.
// ---------------------------------------------------------------------------
__global__ __launch_bounds__(256) void attn_kernel(
    const float* __restrict__ a_g, const float* __restrict__ c_g,
    const float* __restrict__ v_g, const float* __restrict__ b1,
    const float* __restrict__ W2, const float* __restrict__ b2,
    const float* __restrict__ W3, const float* __restrict__ b3,
    short* __restrict__ attnout) {
  const int i = blockIdx.x;
  const int h = blockIdx.y;
  const int tid = threadIdx.x;
  const int w = tid >> 6;
  const int lane = tid & 63;
  const int m = lane & 15;       // j-within-tile for A; q for B/D
  const int quad = lane >> 4;

  __shared__ float sc[N_SEQ];
  __shared__ float red[256];

  const float b2v = b2[m];
  const float w3v = W3[m];
  const float b3v = b3[0];

  // W2 B-fragment (one-time)
  bf16x8 w2f;
  {
    const float4* wp = (const float4*)(W2 + m * P + quad * 8);
    const float4 w0 = wp[0], w1 = wp[1];
    union { bf16x8 v; __hip_bfloat162 h2[4]; } u;
    u.h2[0] = __float22bfloat162_rn(make_float2(w0.x, w0.y));
    u.h2[1] = __float22bfloat162_rn(make_float2(w0.z, w0.w));
    u.h2[2] = __float22bfloat162_rn(make_float2(w1.x, w1.y));
    u.h2[3] = __float22bfloat162_rn(make_float2(w1.z, w1.w));
    w2f = u.v;
  }

  // ab[jj] = a_i[quad*8+jj] + b1[quad*8+jj]
  float ab[8];
  {
    const float4* ap = (const float4*)(a_g + ((size_t)h * N_SEQ + i) * P + quad * 8);
    const float4* bp = (const float4*)(b1 + quad * 8);
    const float4 a0 = ap[0], a1 = ap[1];
    const float4 q0 = bp[0], q1 = bp[1];
    ab[0] = a0.x + q0.x; ab[1] = a0.y + q0.y;
    ab[2] = a0.z + q0.z; ab[3] = a0.w + q0.w;
    ab[4] = a1.x + q1.x; ab[5] = a1.y + q1.y;
    ab[6] = a1.z + q1.z; ab[7] = a1.w + q1.w;
  }

  const int nt = (i >> 4) + 1;          // causal: tiles covering j<=i
  for (int jt = w; jt < nt; jt += 4) {
    const float4* cp = (const float4*)(c_g + ((size_t)h * N_SEQ + jt * 16 + m) * P + quad * 8);
    const float4 c0 = cp[0], c1 = cp[1];
    union { bf16x8 v; __hip_bfloat162 h2[4]; } u;
    u.h2[0] = __float22bfloat162_rn(make_float2(fmaxf(ab[0] + c0.x, 0.f),
                                                fmaxf(ab[1] + c0.y, 0.f)));
    u.h2[1] = __float22bfloat162_rn(make_float2(fmaxf(ab[2] + c0.z, 0.f),
                                                fmaxf(ab[3] + c0.w, 0.f)));
    u.h2[2] = __float22bfloat162_rn(make_float2(fmaxf(ab[4] + c1.x, 0.f),
                                                fmaxf(ab[5] + c1.y, 0.f)));
    u.h2[3] = __float22bfloat162_rn(make_float2(fmaxf(ab[6] + c1.z, 0.f),
                                                fmaxf(ab[7] + c1.w, 0.f)));
    f32x4 acc = {0.f, 0.f, 0.f, 0.f};
    acc = __builtin_amdgcn_mfma_f32_16x16x32_bf16(u.v, w2f, acc, 0, 0, 0);

    float t0 = fmaxf(acc[0] + b2v, 0.f) * w3v;
    float t1 = fmaxf(acc[1] + b2v, 0.f) * w3v;
    float t2 = fmaxf(acc[2] + b2v, 0.f) * w3v;
    float t3 = fmaxf(acc[3] + b2v, 0.f) * w3v;
#pragma unroll
    for (int msk = 1; msk < 16; msk <<= 1) {
      t0 += __shfl_xor(t0, msk);
      t1 += __shfl_xor(t1, msk);
      t2 += __shfl_xor(t2, msk);
      t3 += __shfl_xor(t3, msk);
    }
    if (m == 0) {
      float* scp = sc + jt * 16 + quad * 4;
      scp[0] = t0 + b3v; scp[1] = t1 + b3v;
      scp[2] = t2 + b3v; scp[3] = t3 + b3v;
    }
  }
  __syncthreads();

  // ---- causal softmax over sc[0..i] ----
  const int j0 = tid, j1 = tid + 256;
  const bool act0 = (j0 <= i), act1 = (j1 <= i);
  const float s0 = act0 ? sc[j0] : -1e30f;
  const float s1 = act1 ? sc[j1] : -1e30f;

  red[tid] = fmaxf(s0, s1);
  __syncthreads();
  for (int sft = 128; sft > 0; sft >>= 1) {
    if (tid < sft) red[tid] = fmaxf(red[tid], red[tid + sft]);
    __syncthreads();
  }
  const float rmax = red[0];
  __syncthreads();

  const float e0 = act0 ? __expf(s0 - rmax) : 0.f;
  const float e1 = act1 ? __expf(s1 - rmax) : 0.f;
  sc[j0] = e0;
  sc[j1] = e1;
  red[tid] = e0 + e1;
  __syncthreads();
  for (int sft = 128; sft > 0; sft >>= 1) {
    if (tid < sft) red[tid] += red[tid + sft];
    __syncthreads();
  }
  const float inv = 1.f / red[0];
  __syncthreads();

  // ---- attn @ V ----
  const int d = tid & 63, g = tid >> 6;
  float accv = 0.f;
  for (int j = g; j <= i; j += 4)
    accv += sc[j] * v_g[((size_t)h * N_SEQ + j) * DH + d];
  red[tid] = accv;
  __syncthreads();
  if (tid < 64) {
    const float r = red[tid] + red[tid + 64] + red[tid + 128] + red[tid + 192];
    attnout[(size_t)i * DIM + h * DH + tid] = (short)f2bf(r * inv);
  }
}

// ---------------------------------------------------------------------------
extern "C" void kernel_launch(void* const* d_in, const int* in_sizes, int n_in,
                              void* d_out, int out_size, void* d_ws, size_t ws_size,
                              hipStream_t stream) {
  const float* x    = (const float*)d_in[0];
  const float* Wqkv = (const float*)d_in[1];
  const float* Wout = (const float*)d_in[2];
  const float* Wq   = (const float*)d_in[3];
  const float* bq   = (const float*)d_in[4];
  const float* Wk   = (const float*)d_in[5];
  const float* bk   = (const float*)d_in[6];
  const float* W1   = (const float*)d_in[7];
  const float* b1   = (const float*)d_in[8];
  const float* W2   = (const float*)d_in[9];
  const float* b2   = (const float*)d_in[10];
  const float* W3   = (const float*)d_in[11];
  const float* b3   = (const float*)d_in[12];
  float* out = (float*)d_out;

  float* ws      = (float*)d_ws;
  float* qkv     = ws;                                   // 512*3072 f32
  float* a_buf   = qkv + (size_t)N_SEQ * O3;             // 16*512*32 f32
  float* c_buf   = a_buf + (size_t)HEADS * N_SEQ * P;    // 16*512*32 f32
  float* v_buf   = c_buf + (size_t)HEADS * N_SEQ * P;    // 16*512*64 f32
  short* xb      = (short*)(v_buf + (size_t)HEADS * N_SEQ * DH);
  short* Wqkvb   = xb + (size_t)N_SEQ * DIM;             // 3072*1024 bf16
  short* Woutb   = Wqkvb + (size_t)O3 * DIM;             // 1024*1024 bf16
  short* attnb   = Woutb + (size_t)DIM * DIM;            // 512*1024 bf16

  // 0) convert x, Wqkv, Wout to bf16
  const int n0 = (N_SEQ * DIM) / 4;
  const int n1 = (O3 * DIM) / 4;
  const int n2 = (DIM * DIM) / 4;
  const int totalv = n0 + n1 + n2;
  cvt3_bf16<<<(totalv + 255) / 256, 256, 0, stream>>>(
      (const float4*)x,    (ushort4*)xb,    n0,
      (const float4*)Wqkv, (ushort4*)Wqkvb, n1,
      (const float4*)Wout, (ushort4*)Woutb, n2);

  // 1) QKV GEMM (bf16 mfma)
  {
    const int waves = (N_SEQ / 32) * (O3 / 32);   // 1536
    gemm_mfma_nt2<<<waves / 4, 256, 0, stream>>>(xb, Wqkvb, qkv,
                                                 N_SEQ, O3, DIM);
  }

  // 2) per-position projections -> a, c, v
  proj_kernel<<<N_SEQ, 256, 0, stream>>>(qkv, Wq, bq, Wk, bk, W1,
                                         a_buf, c_buf, v_buf);

  // 3) MLP scores (MFMA) + causal softmax + attn@V
  dim3 g3(N_SEQ, HEADS);
  attn_kernel<<<g3, 256, 0, stream>>>(a_buf, c_buf, v_buf, b1, W2, b2, W3, b3,
                                      attnb);

  // 4) output GEMM (bf16 mfma)
  {
    const int waves = (N_SEQ / 32) * (DIM / 32);  // 512
    gemm_mfma_nt2<<<waves / 4, 256, 0, stream>>>(attnb, Woutb, out,
                                                 N_SEQ, DIM, DIM);
  }
}

// Round 4
// 217.853 us; speedup vs baseline: 2.7151x; 1.1734x over previous
//
#include <hip/hip_runtime.h>
#include <hip/hip_bf16.h>
#include <math.h>

#define N_SEQ 512
#define DIM   1024
#define HEADS 16
#define DH    64
#define P     32
#define P2    16
#define O3    3072   // 3 * HEADS * DH

typedef short bf16x8 __attribute__((ext_vector_type(8)));
typedef float f32x4  __attribute__((ext_vector_type(4)));

__device__ inline unsigned short f2bf(float f) {
  union { float f; unsigned u; } v; v.f = f;
  unsigned r = (v.u + 0x7fffu + ((v.u >> 16) & 1u)) >> 16;
  return (unsigned short)r;
}

// ---------------------------------------------------------------------------
// fp32 -> bf16 (RNE) for three arrays in one launch. Counts in float4s.
// ---------------------------------------------------------------------------
__global__ __launch_bounds__(256) void cvt3_bf16(
    const float4* __restrict__ s0, ushort4* __restrict__ d0, int n0,
    const float4* __restrict__ s1, ushort4* __restrict__ d1, int n1,
    const float4* __restrict__ s2, ushort4* __restrict__ d2, int n2) {
  const int total = n0 + n1 + n2;
  for (int t = blockIdx.x * 256 + threadIdx.x; t < total;
       t += gridDim.x * 256) {
    const float4* s; ushort4* d; int off;
    if (t < n0)            { s = s0; d = d0; off = t; }
    else if (t < n0 + n1)  { s = s1; d = d1; off = t - n0; }
    else                   { s = s2; d = d2; off = t - n0 - n1; }
    const float4 v = s[off];
    ushort4 o;
    o.x = f2bf(v.x); o.y = f2bf(v.y); o.z = f2bf(v.z); o.w = f2bf(v.w);
    d[off] = o;
  }
}

// ---------------------------------------------------------------------------
// bf16 MFMA NT GEMM, 2x2 16-tiles per wave (32x32 out/wave).
// ---------------------------------------------------------------------------
__global__ __launch_bounds__(256) void gemm_mfma_nt2(
    const short* __restrict__ A, const short* __restrict__ B,
    float* __restrict__ C, int M, int N, int K) {
  const int tilesN = N >> 5;
  const int wave = blockIdx.x * 4 + (threadIdx.x >> 6);
  const int tm = wave / tilesN;
  const int tn = wave % tilesN;
  if (tm >= (M >> 5)) return;

  const int lane = threadIdx.x & 63;
  const int m = lane & 15;
  const int quad = lane >> 4;

  const short* pa0 = A + (size_t)(tm * 32 + m) * K + quad * 8;
  const short* pa1 = pa0 + (size_t)16 * K;
  const short* pb0 = B + (size_t)(tn * 32 + m) * K + quad * 8;
  const short* pb1 = pb0 + (size_t)16 * K;

  f32x4 acc00 = {0.f,0.f,0.f,0.f}, acc01 = {0.f,0.f,0.f,0.f};
  f32x4 acc10 = {0.f,0.f,0.f,0.f}, acc11 = {0.f,0.f,0.f,0.f};
#pragma unroll 4
  for (int k = 0; k < K; k += 32) {
    const bf16x8 a0 = *(const bf16x8*)(pa0 + k);
    const bf16x8 a1 = *(const bf16x8*)(pa1 + k);
    const bf16x8 b0 = *(const bf16x8*)(pb0 + k);
    const bf16x8 b1 = *(const bf16x8*)(pb1 + k);
    acc00 = __builtin_amdgcn_mfma_f32_16x16x32_bf16(a0, b0, acc00, 0, 0, 0);
    acc01 = __builtin_amdgcn_mfma_f32_16x16x32_bf16(a0, b1, acc01, 0, 0, 0);
    acc10 = __builtin_amdgcn_mfma_f32_16x16x32_bf16(a1, b0, acc10, 0, 0, 0);
    acc11 = __builtin_amdgcn_mfma_f32_16x16x32_bf16(a1, b1, acc11, 0, 0, 0);
  }

  float* pc00 = C + (size_t)(tm * 32 + quad * 4) * N + tn * 32 + m;
#pragma unroll
  for (int r = 0; r < 4; ++r) {
    pc00[(size_t)r * N]             = acc00[r];
    pc00[(size_t)r * N + 16]        = acc01[r];
    pc00[(size_t)(r + 16) * N]      = acc10[r];
    pc00[(size_t)(r + 16) * N + 16] = acc11[r];
  }
}

// ---------------------------------------------------------------------------
// Fused per-position projections (unchanged).
// ---------------------------------------------------------------------------
__global__ __launch_bounds__(256) void proj_kernel(
    const float* __restrict__ qkv,
    const float* __restrict__ Wq, const float* __restrict__ bq,
    const float* __restrict__ Wk, const float* __restrict__ bk,
    const float* __restrict__ W1,
    float* __restrict__ a_out, float* __restrict__ c_out,
    float* __restrict__ v_out) {
  const int n = blockIdx.x;
  const int tid = threadIdx.x;
  __shared__ float row[O3];
  __shared__ float qp_s[HEADS][P];
  __shared__ float kp_s[HEADS][P];

  for (int t = tid; t < O3; t += 256) row[t] = qkv[(size_t)n * O3 + t];
  __syncthreads();

  for (int t = tid; t < HEADS * P; t += 256) {
    const int h = t >> 5, p = t & 31;
    float sq = bq[p], sk = bk[p];
#pragma unroll
    for (int d = 0; d < DH; ++d) {
      sq += row[d * 48 + h] * Wq[p * DH + d];
      sk += row[d * 48 + 16 + h] * Wk[p * DH + d];
    }
    qp_s[h][p] = sq;
    kp_s[h][p] = sk;
  }
  __syncthreads();

  for (int t = tid; t < HEADS * P; t += 256) {
    const int h = t >> 5, qq = t & 31;
    float sa = 0.f, sc2 = 0.f;
#pragma unroll
    for (int p = 0; p < P; ++p) {
      sa  += qp_s[h][p] * W1[qq * (2 * P) + p];
      sc2 += kp_s[h][p] * W1[qq * (2 * P) + P + p];
    }
    a_out[((size_t)h * N_SEQ + n) * P + qq] = sa;
    c_out[((size_t)h * N_SEQ + n) * P + qq] = sc2;
  }

  for (int t = tid; t < HEADS * DH; t += 256) {
    const int h = t >> 6, d = t & 63;
    v_out[((size_t)h * N_SEQ + n) * DH + d] = row[d * 48 + 32 + h];
  }
}

// ---------------------------------------------------------------------------
// Per (h, i): MFMA MLP scores, wave-level softmax reductions, float4 attn@V.
// Barriers: 4 total (vs ~20 in prior version).
// ---------------------------------------------------------------------------
__global__ __launch_bounds__(256) void attn_kernel(
    const float* __restrict__ a_g, const float* __restrict__ c_g,
    const float* __restrict__ v_g, const float* __restrict__ b1,
    const float* __restrict__ W2, const float* __restrict__ b2,
    const float* __restrict__ W3, const float* __restrict__ b3,
    short* __restrict__ attnout) {
  const int i = blockIdx.x;
  const int h = blockIdx.y;
  const int tid = threadIdx.x;
  const int w = tid >> 6;
  const int lane = tid & 63;
  const int m = lane & 15;       // j-within-tile for A; q for B/D
  const int quad = lane >> 4;

  __shared__ float sc[N_SEQ];
  __shared__ float redm[4], reds[4];
  __shared__ __align__(16) float redv[4][DH];

  const float b2v = b2[m];
  const float w3v = W3[m];
  const float b3v = b3[0];

  // W2 B-fragment (one-time)
  bf16x8 w2f;
  {
    const float4* wp = (const float4*)(W2 + m * P + quad * 8);
    const float4 w0 = wp[0], w1 = wp[1];
    union { bf16x8 v; __hip_bfloat162 h2[4]; } u;
    u.h2[0] = __float22bfloat162_rn(make_float2(w0.x, w0.y));
    u.h2[1] = __float22bfloat162_rn(make_float2(w0.z, w0.w));
    u.h2[2] = __float22bfloat162_rn(make_float2(w1.x, w1.y));
    u.h2[3] = __float22bfloat162_rn(make_float2(w1.z, w1.w));
    w2f = u.v;
  }

  // ab[jj] = a_i[quad*8+jj] + b1[quad*8+jj]
  float ab[8];
  {
    const float4* ap = (const float4*)(a_g + ((size_t)h * N_SEQ + i) * P + quad * 8);
    const float4* bp = (const float4*)(b1 + quad * 8);
    const float4 a0 = ap[0], a1 = ap[1];
    const float4 q0 = bp[0], q1 = bp[1];
    ab[0] = a0.x + q0.x; ab[1] = a0.y + q0.y;
    ab[2] = a0.z + q0.z; ab[3] = a0.w + q0.w;
    ab[4] = a1.x + q1.x; ab[5] = a1.y + q1.y;
    ab[6] = a1.z + q1.z; ab[7] = a1.w + q1.w;
  }

  // ---- phase 1: scores via MFMA ----
  const int nt = (i >> 4) + 1;
#pragma unroll 2
  for (int jt = w; jt < nt; jt += 4) {
    const float4* cp = (const float4*)(c_g + ((size_t)h * N_SEQ + jt * 16 + m) * P + quad * 8);
    const float4 c0 = cp[0], c1 = cp[1];
    union { bf16x8 v; __hip_bfloat162 h2[4]; } u;
    u.h2[0] = __float22bfloat162_rn(make_float2(fmaxf(ab[0] + c0.x, 0.f),
                                                fmaxf(ab[1] + c0.y, 0.f)));
    u.h2[1] = __float22bfloat162_rn(make_float2(fmaxf(ab[2] + c0.z, 0.f),
                                                fmaxf(ab[3] + c0.w, 0.f)));
    u.h2[2] = __float22bfloat162_rn(make_float2(fmaxf(ab[4] + c1.x, 0.f),
                                                fmaxf(ab[5] + c1.y, 0.f)));
    u.h2[3] = __float22bfloat162_rn(make_float2(fmaxf(ab[6] + c1.z, 0.f),
                                                fmaxf(ab[7] + c1.w, 0.f)));
    f32x4 acc = {0.f, 0.f, 0.f, 0.f};
    acc = __builtin_amdgcn_mfma_f32_16x16x32_bf16(u.v, w2f, acc, 0, 0, 0);

    float t0 = fmaxf(acc[0] + b2v, 0.f) * w3v;
    float t1 = fmaxf(acc[1] + b2v, 0.f) * w3v;
    float t2 = fmaxf(acc[2] + b2v, 0.f) * w3v;
    float t3 = fmaxf(acc[3] + b2v, 0.f) * w3v;
#pragma unroll
    for (int msk = 1; msk < 16; msk <<= 1) {
      t0 += __shfl_xor(t0, msk);
      t1 += __shfl_xor(t1, msk);
      t2 += __shfl_xor(t2, msk);
      t3 += __shfl_xor(t3, msk);
    }
    if (m == 0) {
      float* scp = sc + jt * 16 + quad * 4;
      scp[0] = t0 + b3v; scp[1] = t1 + b3v;
      scp[2] = t2 + b3v; scp[3] = t3 + b3v;
    }
  }
  __syncthreads();   // (1) scores visible

  // ---- softmax: wave shfl reductions + 4-element LDS exchange ----
  const int j0 = tid, j1 = tid + 256;
  const bool act0 = (j0 <= i), act1 = (j1 <= i);
  const float s0 = act0 ? sc[j0] : -1e30f;
  const float s1 = act1 ? sc[j1] : -1e30f;

  float mx = fmaxf(s0, s1);
#pragma unroll
  for (int msk = 1; msk < 64; msk <<= 1) mx = fmaxf(mx, __shfl_xor(mx, msk));
  if (lane == 0) redm[w] = mx;
  __syncthreads();   // (2) redm visible; also orders sc reads before writes
  const float rmax = fmaxf(fmaxf(redm[0], redm[1]), fmaxf(redm[2], redm[3]));

  const float e0 = act0 ? __expf(s0 - rmax) : 0.f;
  const float e1 = act1 ? __expf(s1 - rmax) : 0.f;
  float sum = e0 + e1;
#pragma unroll
  for (int msk = 1; msk < 64; msk <<= 1) sum += __shfl_xor(sum, msk);
  if (lane == 0) reds[w] = sum;
  sc[j0] = e0;
  sc[j1] = e1;
  __syncthreads();   // (3) reds + sc(exp) visible
  const float inv = 1.f / (reds[0] + reds[1] + reds[2] + reds[3]);

  // ---- attn @ V: float4 loads, 4 j per wave-instruction ----
  const int jj = lane >> 4;      // j sub-slot (0..3)
  const int dg = lane & 15;      // d-group (4 floats each)
  const float4* vp = (const float4*)(v_g + (size_t)h * N_SEQ * DH);
  float4 acc4 = {0.f, 0.f, 0.f, 0.f};
  for (int j = w * 4 + jj; j <= i; j += 16) {
    const float s = sc[j];
    const float4 v4 = vp[(size_t)j * 16 + dg];
    acc4.x += s * v4.x; acc4.y += s * v4.y;
    acc4.z += s * v4.z; acc4.w += s * v4.w;
  }
#pragma unroll
  for (int msk = 16; msk < 64; msk <<= 1) {
    acc4.x += __shfl_xor(acc4.x, msk);
    acc4.y += __shfl_xor(acc4.y, msk);
    acc4.z += __shfl_xor(acc4.z, msk);
    acc4.w += __shfl_xor(acc4.w, msk);
  }
  if (jj == 0) *(float4*)&redv[w][dg * 4] = acc4;
  __syncthreads();   // (4) redv visible

  if (tid < DH) {
    const float r = redv[0][tid] + redv[1][tid] + redv[2][tid] + redv[3][tid];
    attnout[(size_t)i * DIM + h * DH + tid] = (short)f2bf(r * inv);
  }
}

// ---------------------------------------------------------------------------
extern "C" void kernel_launch(void* const* d_in, const int* in_sizes, int n_in,
                              void* d_out, int out_size, void* d_ws, size_t ws_size,
                              hipStream_t stream) {
  const float* x    = (const float*)d_in[0];
  const float* Wqkv = (const float*)d_in[1];
  const float* Wout = (const float*)d_in[2];
  const float* Wq   = (const float*)d_in[3];
  const float* bq   = (const float*)d_in[4];
  const float* Wk   = (const float*)d_in[5];
  const float* bk   = (const float*)d_in[6];
  const float* W1   = (const float*)d_in[7];
  const float* b1   = (const float*)d_in[8];
  const float* W2   = (const float*)d_in[9];
  const float* b2   = (const float*)d_in[10];
  const float* W3   = (const float*)d_in[11];
  const float* b3   = (const float*)d_in[12];
  float* out = (float*)d_out;

  float* ws      = (float*)d_ws;
  float* qkv     = ws;                                   // 512*3072 f32
  float* a_buf   = qkv + (size_t)N_SEQ * O3;             // 16*512*32 f32
  float* c_buf   = a_buf + (size_t)HEADS * N_SEQ * P;    // 16*512*32 f32
  float* v_buf   = c_buf + (size_t)HEADS * N_SEQ * P;    // 16*512*64 f32
  short* xb      = (short*)(v_buf + (size_t)HEADS * N_SEQ * DH);
  short* Wqkvb   = xb + (size_t)N_SEQ * DIM;             // 3072*1024 bf16
  short* Woutb   = Wqkvb + (size_t)O3 * DIM;             // 1024*1024 bf16
  short* attnb   = Woutb + (size_t)DIM * DIM;            // 512*1024 bf16

  // 0) convert x, Wqkv, Wout to bf16
  const int n0 = (N_SEQ * DIM) / 4;
  const int n1 = (O3 * DIM) / 4;
  const int n2 = (DIM * DIM) / 4;
  const int totalv = n0 + n1 + n2;
  cvt3_bf16<<<(totalv + 255) / 256, 256, 0, stream>>>(
      (const float4*)x,    (ushort4*)xb,    n0,
      (const float4*)Wqkv, (ushort4*)Wqkvb, n1,
      (const float4*)Wout, (ushort4*)Woutb, n2);

  // 1) QKV GEMM (bf16 mfma)
  {
    const int waves = (N_SEQ / 32) * (O3 / 32);   // 1536
    gemm_mfma_nt2<<<waves / 4, 256, 0, stream>>>(xb, Wqkvb, qkv,
                                                 N_SEQ, O3, DIM);
  }

  // 2) per-position projections -> a, c, v
  proj_kernel<<<N_SEQ, 256, 0, stream>>>(qkv, Wq, bq, Wk, bk, W1,
                                         a_buf, c_buf, v_buf);

  // 3) MLP scores (MFMA) + causal softmax + attn@V
  dim3 g3(N_SEQ, HEADS);
  attn_kernel<<<g3, 256, 0, stream>>>(a_buf, c_buf, v_buf, b1, W2, b2, W3, b3,
                                      attnb);

  // 4) output GEMM (bf16 mfma)
  {
    const int waves = (N_SEQ / 32) * (DIM / 32);  // 512
    gemm_mfma_nt2<<<waves / 4, 256, 0, stream>>>(attnb, Woutb, out,
                                                 N_SEQ, DIM, DIM);
  }
}

// Round 5
// 210.651 us; speedup vs baseline: 2.8079x; 1.0342x over previous
//
#include <hip/hip_runtime.h>
#include <hip/hip_bf16.h>
#include <math.h>

#define N_SEQ 512
#define DIM   1024
#define HEADS 16
#define DH    64
#define P     32
#define P2    16
#define O3    3072   // 3 * HEADS * DH

typedef short bf16x8 __attribute__((ext_vector_type(8)));
typedef float f32x4  __attribute__((ext_vector_type(4)));

__device__ inline unsigned short f2bf(float f) {
  union { float f; unsigned u; } v; v.f = f;
  unsigned r = (v.u + 0x7fffu + ((v.u >> 16) & 1u)) >> 16;
  return (unsigned short)r;
}

// ---------------------------------------------------------------------------
// fp32 -> bf16 (RNE) for three arrays in one launch. Counts in float4s.
// ---------------------------------------------------------------------------
__global__ __launch_bounds__(256) void cvt3_bf16(
    const float4* __restrict__ s0, ushort4* __restrict__ d0, int n0,
    const float4* __restrict__ s1, ushort4* __restrict__ d1, int n1,
    const float4* __restrict__ s2, ushort4* __restrict__ d2, int n2) {
  const int total = n0 + n1 + n2;
  for (int t = blockIdx.x * 256 + threadIdx.x; t < total;
       t += gridDim.x * 256) {
    const float4* s; ushort4* d; int off;
    if (t < n0)            { s = s0; d = d0; off = t; }
    else if (t < n0 + n1)  { s = s1; d = d1; off = t - n0; }
    else                   { s = s2; d = d2; off = t - n0 - n1; }
    const float4 v = s[off];
    ushort4 o;
    o.x = f2bf(v.x); o.y = f2bf(v.y); o.z = f2bf(v.z); o.w = f2bf(v.w);
    d[off] = o;
  }
}

// ---------------------------------------------------------------------------
// bf16 MFMA NT GEMM, 2x2 16-tiles per wave (32x32 out/wave), K-split.
// SPLITK>1 accumulates via atomicAdd (C must be zeroed first).
// ---------------------------------------------------------------------------
template<int SPLITK>
__global__ __launch_bounds__(256) void gemm_mfma_nt2(
    const short* __restrict__ A, const short* __restrict__ B,
    float* __restrict__ C, int M, int N, int K) {
  const int tilesN = N >> 5;
  const int tilesM = M >> 5;
  int wave = blockIdx.x * 4 + (threadIdx.x >> 6);
  const int kslice = wave / (tilesM * tilesN);
  wave %= tilesM * tilesN;
  const int tm = wave / tilesN;
  const int tn = wave % tilesN;

  const int lane = threadIdx.x & 63;
  const int m = lane & 15;
  const int quad = lane >> 4;

  const int Ks = K / SPLITK;
  const int k0 = kslice * Ks;

  const short* pa0 = A + (size_t)(tm * 32 + m) * K + k0 + quad * 8;
  const short* pa1 = pa0 + (size_t)16 * K;
  const short* pb0 = B + (size_t)(tn * 32 + m) * K + k0 + quad * 8;
  const short* pb1 = pb0 + (size_t)16 * K;

  f32x4 acc00 = {0.f,0.f,0.f,0.f}, acc01 = {0.f,0.f,0.f,0.f};
  f32x4 acc10 = {0.f,0.f,0.f,0.f}, acc11 = {0.f,0.f,0.f,0.f};
#pragma unroll 4
  for (int k = 0; k < Ks; k += 32) {
    const bf16x8 a0 = *(const bf16x8*)(pa0 + k);
    const bf16x8 a1 = *(const bf16x8*)(pa1 + k);
    const bf16x8 b0 = *(const bf16x8*)(pb0 + k);
    const bf16x8 b1 = *(const bf16x8*)(pb1 + k);
    acc00 = __builtin_amdgcn_mfma_f32_16x16x32_bf16(a0, b0, acc00, 0, 0, 0);
    acc01 = __builtin_amdgcn_mfma_f32_16x16x32_bf16(a0, b1, acc01, 0, 0, 0);
    acc10 = __builtin_amdgcn_mfma_f32_16x16x32_bf16(a1, b0, acc10, 0, 0, 0);
    acc11 = __builtin_amdgcn_mfma_f32_16x16x32_bf16(a1, b1, acc11, 0, 0, 0);
  }

  float* pc00 = C + (size_t)(tm * 32 + quad * 4) * N + tn * 32 + m;
#pragma unroll
  for (int r = 0; r < 4; ++r) {
    if (SPLITK == 1) {
      pc00[(size_t)r * N]             = acc00[r];
      pc00[(size_t)r * N + 16]        = acc01[r];
      pc00[(size_t)(r + 16) * N]      = acc10[r];
      pc00[(size_t)(r + 16) * N + 16] = acc11[r];
    } else {
      atomicAdd(&pc00[(size_t)r * N],             acc00[r]);
      atomicAdd(&pc00[(size_t)r * N + 16],        acc01[r]);
      atomicAdd(&pc00[(size_t)(r + 16) * N],      acc10[r]);
      atomicAdd(&pc00[(size_t)(r + 16) * N + 16], acc11[r]);
    }
  }
}

// ---------------------------------------------------------------------------
// Fused per-position projections (unchanged).
// ---------------------------------------------------------------------------
__global__ __launch_bounds__(256) void proj_kernel(
    const float* __restrict__ qkv,
    const float* __restrict__ Wq, const float* __restrict__ bq,
    const float* __restrict__ Wk, const float* __restrict__ bk,
    const float* __restrict__ W1,
    float* __restrict__ a_out, float* __restrict__ c_out,
    float* __restrict__ v_out) {
  const int n = blockIdx.x;
  const int tid = threadIdx.x;
  __shared__ float row[O3];
  __shared__ float qp_s[HEADS][P];
  __shared__ float kp_s[HEADS][P];

  for (int t = tid; t < O3; t += 256) row[t] = qkv[(size_t)n * O3 + t];
  __syncthreads();

  for (int t = tid; t < HEADS * P; t += 256) {
    const int h = t >> 5, p = t & 31;
    float sq = bq[p], sk = bk[p];
#pragma unroll
    for (int d = 0; d < DH; ++d) {
      sq += row[d * 48 + h] * Wq[p * DH + d];
      sk += row[d * 48 + 16 + h] * Wk[p * DH + d];
    }
    qp_s[h][p] = sq;
    kp_s[h][p] = sk;
  }
  __syncthreads();

  for (int t = tid; t < HEADS * P; t += 256) {
    const int h = t >> 5, qq = t & 31;
    float sa = 0.f, sc2 = 0.f;
#pragma unroll
    for (int p = 0; p < P; ++p) {
      sa  += qp_s[h][p] * W1[qq * (2 * P) + p];
      sc2 += kp_s[h][p] * W1[qq * (2 * P) + P + p];
    }
    a_out[((size_t)h * N_SEQ + n) * P + qq] = sa;
    c_out[((size_t)h * N_SEQ + n) * P + qq] = sc2;
  }

  for (int t = tid; t < HEADS * DH; t += 256) {
    const int h = t >> 6, d = t & 63;
    v_out[((size_t)h * N_SEQ + n) * DH + d] = row[d * 48 + 32 + h];
  }
}

// ---------------------------------------------------------------------------
// Block = (h, tile of 8 i-rows). 4 waves x 2 rows each.
// Phase 1: scores via operand-swapped MFMA: D[q][j] = mfma(W2frag, h1frag)
//          -> q in register dim; reduction = 4 in-lane FMA + 2 shfl_xor.
// Phase 2: per-row softmax (32 threads/row, 5-step shfl).
// Phase 3: attn@V with float4 V loads shared by 2 rows.
// ---------------------------------------------------------------------------
__global__ __launch_bounds__(256) void attn_kernel(
    const float* __restrict__ a_g, const float* __restrict__ c_g,
    const float* __restrict__ v_g, const float* __restrict__ b1,
    const float* __restrict__ W2, const float* __restrict__ b2,
    const float* __restrict__ W3, const float* __restrict__ b3,
    short* __restrict__ attnout) {
  const int it = blockIdx.x;           // 8-row i-tile
  const int h  = blockIdx.y;
  const int tid = threadIdx.x;
  const int w = tid >> 6;
  const int lane = tid & 63;
  const int m = lane & 15;
  const int quad = lane >> 4;

  const int i0 = it * 8;
  const int imax = i0 + 7;
  const int nt = (imax >> 4) + 1;      // 16-wide j-tiles to compute
  const int jlim = nt * 16;

  __shared__ float sc[8][N_SEQ];       // 16 KB
  __shared__ float invr[8];

  // W2 A-fragment: A[q=m][p=quad*8+jj]
  bf16x8 w2f;
  {
    const float4* wp = (const float4*)(W2 + m * P + quad * 8);
    const float4 w0 = wp[0], w1 = wp[1];
    union { bf16x8 v; __hip_bfloat162 h2[4]; } u;
    u.h2[0] = __float22bfloat162_rn(make_float2(w0.x, w0.y));
    u.h2[1] = __float22bfloat162_rn(make_float2(w0.z, w0.w));
    u.h2[2] = __float22bfloat162_rn(make_float2(w1.x, w1.y));
    u.h2[3] = __float22bfloat162_rn(make_float2(w1.z, w1.w));
    w2f = u.v;
  }
  const float4 b2q = *(const float4*)(b2 + quad * 4);
  const float4 w3q = *(const float4*)(W3 + quad * 4);
  const float b3v = b3[0];

  // this wave's two rows (local r0,r1 / global gi0,gi1)
  const int r0 = w * 2, r1 = r0 + 1;
  const int gi0 = i0 + r0, gi1 = i0 + r1;

  float ab0[8], ab1[8];
  {
    const float4* bp = (const float4*)(b1 + quad * 8);
    const float4 q0 = bp[0], q1 = bp[1];
    const float4* a0p = (const float4*)(a_g + ((size_t)h * N_SEQ + gi0) * P + quad * 8);
    const float4* a1p = (const float4*)(a_g + ((size_t)h * N_SEQ + gi1) * P + quad * 8);
    const float4 a00 = a0p[0], a01 = a0p[1];
    const float4 a10 = a1p[0], a11 = a1p[1];
    ab0[0] = a00.x + q0.x; ab0[1] = a00.y + q0.y;
    ab0[2] = a00.z + q0.z; ab0[3] = a00.w + q0.w;
    ab0[4] = a01.x + q1.x; ab0[5] = a01.y + q1.y;
    ab0[6] = a01.z + q1.z; ab0[7] = a01.w + q1.w;
    ab1[0] = a10.x + q0.x; ab1[1] = a10.y + q0.y;
    ab1[2] = a10.z + q0.z; ab1[3] = a10.w + q0.w;
    ab1[4] = a11.x + q1.x; ab1[5] = a11.y + q1.y;
    ab1[6] = a11.z + q1.z; ab1[7] = a11.w + q1.w;
  }

  // ---- phase 1: scores ----
#pragma unroll 2
  for (int jt = 0; jt < nt; ++jt) {
    const float4* cp = (const float4*)(c_g + ((size_t)h * N_SEQ + jt * 16 + m) * P + quad * 8);
    const float4 c0 = cp[0], c1 = cp[1];

    union { bf16x8 v; __hip_bfloat162 h2[4]; } u0, u1;
    u0.h2[0] = __float22bfloat162_rn(make_float2(fmaxf(ab0[0] + c0.x, 0.f),
                                                 fmaxf(ab0[1] + c0.y, 0.f)));
    u0.h2[1] = __float22bfloat162_rn(make_float2(fmaxf(ab0[2] + c0.z, 0.f),
                                                 fmaxf(ab0[3] + c0.w, 0.f)));
    u0.h2[2] = __float22bfloat162_rn(make_float2(fmaxf(ab0[4] + c1.x, 0.f),
                                                 fmaxf(ab0[5] + c1.y, 0.f)));
    u0.h2[3] = __float22bfloat162_rn(make_float2(fmaxf(ab0[6] + c1.z, 0.f),
                                                 fmaxf(ab0[7] + c1.w, 0.f)));
    u1.h2[0] = __float22bfloat162_rn(make_float2(fmaxf(ab1[0] + c0.x, 0.f),
                                                 fmaxf(ab1[1] + c0.y, 0.f)));
    u1.h2[1] = __float22bfloat162_rn(make_float2(fmaxf(ab1[2] + c0.z, 0.f),
                                                 fmaxf(ab1[3] + c0.w, 0.f)));
    u1.h2[2] = __float22bfloat162_rn(make_float2(fmaxf(ab1[4] + c1.x, 0.f),
                                                 fmaxf(ab1[5] + c1.y, 0.f)));
    u1.h2[3] = __float22bfloat162_rn(make_float2(fmaxf(ab1[6] + c1.z, 0.f),
                                                 fmaxf(ab1[7] + c1.w, 0.f)));

    f32x4 acc0 = {0.f,0.f,0.f,0.f}, acc1 = {0.f,0.f,0.f,0.f};
    acc0 = __builtin_amdgcn_mfma_f32_16x16x32_bf16(w2f, u0.v, acc0, 0, 0, 0);
    acc1 = __builtin_amdgcn_mfma_f32_16x16x32_bf16(w2f, u1.v, acc1, 0, 0, 0);

    // t = sum_r relu(acc[r] + b2[quad*4+r]) * W3[quad*4+r]
    float t0 = fmaxf(acc0[0] + b2q.x, 0.f) * w3q.x
             + fmaxf(acc0[1] + b2q.y, 0.f) * w3q.y
             + fmaxf(acc0[2] + b2q.z, 0.f) * w3q.z
             + fmaxf(acc0[3] + b2q.w, 0.f) * w3q.w;
    float t1 = fmaxf(acc1[0] + b2q.x, 0.f) * w3q.x
             + fmaxf(acc1[1] + b2q.y, 0.f) * w3q.y
             + fmaxf(acc1[2] + b2q.z, 0.f) * w3q.z
             + fmaxf(acc1[3] + b2q.w, 0.f) * w3q.w;
    t0 += __shfl_xor(t0, 16); t0 += __shfl_xor(t0, 32);
    t1 += __shfl_xor(t1, 16); t1 += __shfl_xor(t1, 32);

    if (quad == 0)      sc[r0][jt * 16 + m] = t0 + b3v;
    else if (quad == 1) sc[r1][jt * 16 + m] = t1 + b3v;
  }
  __syncthreads();

  // ---- phase 2: per-row softmax (32 threads / row) ----
  {
    const int row = tid >> 5, sl = tid & 31;
    const int ig = i0 + row;
    float mx = -1e30f;
    for (int j = sl; j < jlim; j += 32) {
      const float s = (j <= ig) ? sc[row][j] : -1e30f;
      mx = fmaxf(mx, s);
    }
#pragma unroll
    for (int msk = 1; msk < 32; msk <<= 1) mx = fmaxf(mx, __shfl_xor(mx, msk));
    float sum = 0.f;
    for (int j = sl; j < jlim; j += 32) {
      const float e = (j <= ig) ? __expf(sc[row][j] - mx) : 0.f;
      sc[row][j] = e;
      sum += e;
    }
#pragma unroll
    for (int msk = 1; msk < 32; msk <<= 1) sum += __shfl_xor(sum, msk);
    if (sl == 0) invr[row] = 1.f / sum;
  }
  __syncthreads();

  // ---- phase 3: attn @ V (wave w -> rows r0, r1) ----
  {
    const int jj = lane >> 4;       // j sub-slot (0..3)
    const int dg = m;               // d-group (4 floats)
    const float4* vp = (const float4*)(v_g + (size_t)h * N_SEQ * DH);
    float4 A0 = {0.f,0.f,0.f,0.f}, A1 = {0.f,0.f,0.f,0.f};
    for (int j = jj; j <= gi1; j += 4) {
      const float4 v4 = vp[(size_t)j * 16 + dg];
      const float s0 = sc[r0][j];   // zeroed beyond gi0 by phase 2
      const float s1 = sc[r1][j];
      A0.x += s0 * v4.x; A0.y += s0 * v4.y; A0.z += s0 * v4.z; A0.w += s0 * v4.w;
      A1.x += s1 * v4.x; A1.y += s1 * v4.y; A1.z += s1 * v4.z; A1.w += s1 * v4.w;
    }
#pragma unroll
    for (int msk = 16; msk < 64; msk <<= 1) {
      A0.x += __shfl_xor(A0.x, msk); A0.y += __shfl_xor(A0.y, msk);
      A0.z += __shfl_xor(A0.z, msk); A0.w += __shfl_xor(A0.w, msk);
      A1.x += __shfl_xor(A1.x, msk); A1.y += __shfl_xor(A1.y, msk);
      A1.z += __shfl_xor(A1.z, msk); A1.w += __shfl_xor(A1.w, msk);
    }
    if (jj == 0) {
      const float inv0 = invr[r0], inv1 = invr[r1];
      ushort4 o0, o1;
      o0.x = f2bf(A0.x * inv0); o0.y = f2bf(A0.y * inv0);
      o0.z = f2bf(A0.z * inv0); o0.w = f2bf(A0.w * inv0);
      o1.x = f2bf(A1.x * inv1); o1.y = f2bf(A1.y * inv1);
      o1.z = f2bf(A1.z * inv1); o1.w = f2bf(A1.w * inv1);
      *(ushort4*)(attnout + (size_t)gi0 * DIM + h * DH + dg * 4) = o0;
      *(ushort4*)(attnout + (size_t)gi1 * DIM + h * DH + dg * 4) = o1;
    }
  }
}

// ---------------------------------------------------------------------------
extern "C" void kernel_launch(void* const* d_in, const int* in_sizes, int n_in,
                              void* d_out, int out_size, void* d_ws, size_t ws_size,
                              hipStream_t stream) {
  const float* x    = (const float*)d_in[0];
  const float* Wqkv = (const float*)d_in[1];
  const float* Wout = (const float*)d_in[2];
  const float* Wq   = (const float*)d_in[3];
  const float* bq   = (const float*)d_in[4];
  const float* Wk   = (const float*)d_in[5];
  const float* bk   = (const float*)d_in[6];
  const float* W1   = (const float*)d_in[7];
  const float* b1   = (const float*)d_in[8];
  const float* W2   = (const float*)d_in[9];
  const float* b2   = (const float*)d_in[10];
  const float* W3   = (const float*)d_in[11];
  const float* b3   = (const float*)d_in[12];
  float* out = (float*)d_out;

  float* ws      = (float*)d_ws;
  float* qkv     = ws;                                   // 512*3072 f32
  float* a_buf   = qkv + (size_t)N_SEQ * O3;             // 16*512*32 f32
  float* c_buf   = a_buf + (size_t)HEADS * N_SEQ * P;    // 16*512*32 f32
  float* v_buf   = c_buf + (size_t)HEADS * N_SEQ * P;    // 16*512*64 f32
  short* xb      = (short*)(v_buf + (size_t)HEADS * N_SEQ * DH);
  short* Wqkvb   = xb + (size_t)N_SEQ * DIM;             // 3072*1024 bf16
  short* Woutb   = Wqkvb + (size_t)O3 * DIM;             // 1024*1024 bf16
  short* attnb   = Woutb + (size_t)DIM * DIM;            // 512*1024 bf16

  // 0) convert x, Wqkv, Wout to bf16; zero split-K accumulators
  hipMemsetAsync(qkv, 0, (size_t)N_SEQ * O3 * sizeof(float), stream);
  hipMemsetAsync(out, 0, (size_t)N_SEQ * DIM * sizeof(float), stream);
  const int n0 = (N_SEQ * DIM) / 4;
  const int n1 = (O3 * DIM) / 4;
  const int n2 = (DIM * DIM) / 4;
  const int totalv = n0 + n1 + n2;
  cvt3_bf16<<<(totalv + 255) / 256, 256, 0, stream>>>(
      (const float4*)x,    (ushort4*)xb,    n0,
      (const float4*)Wqkv, (ushort4*)Wqkvb, n1,
      (const float4*)Wout, (ushort4*)Woutb, n2);

  // 1) QKV GEMM (bf16 mfma, K-split 2): 3072 waves -> 768 blocks
  {
    const int waves = (N_SEQ / 32) * (O3 / 32) * 2;
    gemm_mfma_nt2<2><<<waves / 4, 256, 0, stream>>>(xb, Wqkvb, qkv,
                                                    N_SEQ, O3, DIM);
  }

  // 2) per-position projections -> a, c, v
  proj_kernel<<<N_SEQ, 256, 0, stream>>>(qkv, Wq, bq, Wk, bk, W1,
                                         a_buf, c_buf, v_buf);

  // 3) MLP scores (MFMA) + causal softmax + attn@V; 8-row i-tiles
  dim3 g3(N_SEQ / 8, HEADS);
  attn_kernel<<<g3, 256, 0, stream>>>(a_buf, c_buf, v_buf, b1, W2, b2, W3, b3,
                                      attnb);

  // 4) output GEMM (bf16 mfma, K-split 4): 2048 waves -> 512 blocks
  {
    const int waves = (N_SEQ / 32) * (DIM / 32) * 4;
    gemm_mfma_nt2<4><<<waves / 4, 256, 0, stream>>>(attnb, Woutb, out,
                                                    N_SEQ, DIM, DIM);
  }
}

// Round 6
// 205.138 us; speedup vs baseline: 2.8834x; 1.0269x over previous
//
#include <hip/hip_runtime.h>
#include <hip/hip_bf16.h>
#include <math.h>

#define N_SEQ 512
#define DIM   1024
#define HEADS 16
#define DH    64
#define P     32
#define P2    16
#define O3    3072

typedef short bf16x8 __attribute__((ext_vector_type(8)));
typedef float f32x4  __attribute__((ext_vector_type(4)));

__device__ inline unsigned short f2bf(float f) {
  union { float f; unsigned u; } v; v.f = f;
  unsigned r = (v.u + 0x7fffu + ((v.u >> 16) & 1u)) >> 16;
  return (unsigned short)r;
}

// ---------------------------------------------------------------------------
// fp32 -> bf16 cast, three arrays (counts in float4 units).
// ---------------------------------------------------------------------------
__global__ __launch_bounds__(256) void cvt3_bf16(
    const float4* __restrict__ s0, ushort4* __restrict__ d0, int n0,
    const float4* __restrict__ s1, ushort4* __restrict__ d1, int n1,
    const float4* __restrict__ s2, ushort4* __restrict__ d2, int n2) {
  const int total = n0 + n1 + n2;
  for (int t = blockIdx.x * 256 + threadIdx.x; t < total;
       t += gridDim.x * 256) {
    const float4* s; ushort4* d; int off;
    if (t < n0)            { s = s0; d = d0; off = t; }
    else if (t < n0 + n1)  { s = s1; d = d1; off = t - n0; }
    else                   { s = s2; d = d2; off = t - n0 - n1; }
    const float4 v = s[off];
    ushort4 o;
    o.x = f2bf(v.x); o.y = f2bf(v.y); o.z = f2bf(v.z); o.w = f2bf(v.w);
    d[off] = o;
  }
}

// ---------------------------------------------------------------------------
// Folded small weights: Wa = W1q@Wq (32x64), Wc = W1k@Wk, ba32 = W1q@bq,
// bc32 = W1k@bk.  One block, 256 threads.
// ---------------------------------------------------------------------------
__global__ __launch_bounds__(256) void prep_small(
    const float* __restrict__ Wq, const float* __restrict__ bq,
    const float* __restrict__ Wk, const float* __restrict__ bk,
    const float* __restrict__ W1,
    float* __restrict__ Wa, float* __restrict__ Wc,
    float* __restrict__ ba32, float* __restrict__ bc32) {
  const int t = threadIdx.x;
  for (int idx = t; idx < 2048; idx += 256) {
    const int q = idx >> 6, d = idx & 63;
    float sa = 0.f, sc = 0.f;
#pragma unroll
    for (int p = 0; p < 32; ++p) {
      sa += W1[q * 64 + p]      * Wq[p * 64 + d];
      sc += W1[q * 64 + 32 + p] * Wk[p * 64 + d];
    }
    Wa[idx] = sa; Wc[idx] = sc;
  }
  if (t < 32) {
    float sa = 0.f, sc = 0.f;
#pragma unroll
    for (int p = 0; p < 32; ++p) {
      sa += W1[t * 64 + p]      * bq[p];
      sc += W1[t * 64 + 32 + p] * bk[p];
    }
    ba32[t] = sa; bc32[t] = sc;
  }
}

// ---------------------------------------------------------------------------
// Build Wcomb (2048x1024 bf16):
//  rows [0,512):    Wxa[h*32+q][c] = sum_d Wa[q][d] * Wqkv[(d*48+h)][c]
//  rows [512,1024): Wxc[h*32+q][c] = sum_d Wc[q][d] * Wqkv[(d*48+16+h)][c]
//  rows [1024,2048): Wxv[h*64+d][c] = Wqkv[(d*48+32+h)][c]
// blocks 0..255: (part,h,128-col chunk); blocks 256..511: v-rows cast.
// ---------------------------------------------------------------------------
__global__ __launch_bounds__(256) void prep_big(
    const float* __restrict__ Wqkv, const float* __restrict__ Wa,
    const float* __restrict__ Wc, short* __restrict__ Wcomb) {
  const int b = blockIdx.x;
  const int tid = threadIdx.x;
  if (b < 256) {
    const int part = b >> 7;          // 0=a, 1=c
    const int rem = b & 127;
    const int h = rem >> 3, chunk = rem & 7;
    const int c0 = chunk * 128;
    const int grow = (part == 0) ? h : 16 + h;
    __shared__ float qs[64][128];     // 32 KB
    __shared__ float wsm[32][64];     // 8 KB
    for (int idx = tid; idx < 64 * 32; idx += 256) {
      const int d = idx >> 5, c4 = idx & 31;
      const float4 v = *(const float4*)(Wqkv + (size_t)(d * 48 + grow) * 1024 + c0 + c4 * 4);
      *(float4*)&qs[d][c4 * 4] = v;
    }
    const float* Wx = (part == 0) ? Wa : Wc;
    for (int idx = tid; idx < 2048; idx += 256) wsm[idx >> 6][idx & 63] = Wx[idx];
    __syncthreads();
    for (int idx = tid; idx < 32 * 128; idx += 256) {
      const int q = idx >> 7, c = idx & 127;
      float acc = 0.f;
#pragma unroll
      for (int d = 0; d < 64; ++d) acc += wsm[q][d] * qs[d][c];
      const int o = part * 512 + h * 32 + q;
      Wcomb[(size_t)o * 1024 + c0 + c] = (short)f2bf(acc);
    }
  } else {
    const int b2 = b - 256;           // 4 v-rows per block
#pragma unroll
    for (int rr = 0; rr < 4; ++rr) {
      const int ov = b2 * 4 + rr;
      const int h = ov >> 6, d = ov & 63;
      const float4 v = *(const float4*)(Wqkv + (size_t)(d * 48 + 32 + h) * 1024 + tid * 4);
      ushort4 o4;
      o4.x = f2bf(v.x); o4.y = f2bf(v.y); o4.z = f2bf(v.z); o4.w = f2bf(v.w);
      *(ushort4*)(Wcomb + (size_t)(1024 + ov) * 1024 + tid * 4) = o4;
    }
  }
}

// ---------------------------------------------------------------------------
// Main GEMM: Y(512x2048) = xb(512x1024) @ Wcomb^T, scatter into a/c/v bufs
// with folded biases. 16x32 tile per wave, 2048 waves = 512 blocks.
// ---------------------------------------------------------------------------
__global__ __launch_bounds__(256) void gemm_acv(
    const short* __restrict__ xb, const short* __restrict__ Wcomb,
    const float* __restrict__ ba32, const float* __restrict__ bc32,
    float* __restrict__ a_buf, float* __restrict__ c_buf,
    float* __restrict__ v_buf) {
  const int tilesN = 64;
  const int wave = blockIdx.x * 4 + (threadIdx.x >> 6);
  const int tm = wave / tilesN;     // 0..31
  const int tn = wave % tilesN;

  const int lane = threadIdx.x & 63;
  const int m = lane & 15;
  const int quad = lane >> 4;

  const short* pa  = xb + (size_t)(tm * 16 + m) * DIM + quad * 8;
  const short* pb0 = Wcomb + (size_t)(tn * 32 + m) * DIM + quad * 8;
  const short* pb1 = pb0 + (size_t)16 * DIM;

  f32x4 acc0 = {0.f,0.f,0.f,0.f}, acc1 = {0.f,0.f,0.f,0.f};
#pragma unroll 4
  for (int k = 0; k < DIM; k += 32) {
    const bf16x8 av = *(const bf16x8*)(pa + k);
    const bf16x8 b0 = *(const bf16x8*)(pb0 + k);
    const bf16x8 b1 = *(const bf16x8*)(pb1 + k);
    acc0 = __builtin_amdgcn_mfma_f32_16x16x32_bf16(av, b0, acc0, 0, 0, 0);
    acc1 = __builtin_amdgcn_mfma_f32_16x16x32_bf16(av, b1, acc1, 0, 0, 0);
  }

#pragma unroll
  for (int r = 0; r < 4; ++r) {
    const int n = tm * 16 + quad * 4 + r;
#pragma unroll
    for (int half = 0; half < 2; ++half) {
      const int o = tn * 32 + m + half * 16;
      const float val = half ? acc1[r] : acc0[r];
      if (o < 512) {
        const int h = o >> 5, q = o & 31;
        a_buf[(size_t)((h << 9) + n) * P + q] = val + ba32[q];
      } else if (o < 1024) {
        const int oo = o - 512, h = oo >> 5, q = oo & 31;
        c_buf[(size_t)((h << 9) + n) * P + q] = val + bc32[q];
      } else {
        const int ov = o - 1024, h = ov >> 6, d = ov & 63;
        v_buf[(size_t)((h << 9) + n) * DH + d] = val;
      }
    }
  }
}

// ---------------------------------------------------------------------------
// Output GEMM (unchanged, split-K with atomics).
// ---------------------------------------------------------------------------
template<int SPLITK>
__global__ __launch_bounds__(256) void gemm_mfma_nt2(
    const short* __restrict__ A, const short* __restrict__ B,
    float* __restrict__ C, int M, int N, int K) {
  const int tilesN = N >> 5;
  const int tilesM = M >> 5;
  int wave = blockIdx.x * 4 + (threadIdx.x >> 6);
  const int kslice = wave / (tilesM * tilesN);
  wave %= tilesM * tilesN;
  const int tm = wave / tilesN;
  const int tn = wave % tilesN;

  const int lane = threadIdx.x & 63;
  const int m = lane & 15;
  const int quad = lane >> 4;

  const int Ks = K / SPLITK;
  const int k0 = kslice * Ks;

  const short* pa0 = A + (size_t)(tm * 32 + m) * K + k0 + quad * 8;
  const short* pa1 = pa0 + (size_t)16 * K;
  const short* pb0 = B + (size_t)(tn * 32 + m) * K + k0 + quad * 8;
  const short* pb1 = pb0 + (size_t)16 * K;

  f32x4 acc00 = {0.f,0.f,0.f,0.f}, acc01 = {0.f,0.f,0.f,0.f};
  f32x4 acc10 = {0.f,0.f,0.f,0.f}, acc11 = {0.f,0.f,0.f,0.f};
#pragma unroll 4
  for (int k = 0; k < Ks; k += 32) {
    const bf16x8 a0 = *(const bf16x8*)(pa0 + k);
    const bf16x8 a1 = *(const bf16x8*)(pa1 + k);
    const bf16x8 b0 = *(const bf16x8*)(pb0 + k);
    const bf16x8 b1 = *(const bf16x8*)(pb1 + k);
    acc00 = __builtin_amdgcn_mfma_f32_16x16x32_bf16(a0, b0, acc00, 0, 0, 0);
    acc01 = __builtin_amdgcn_mfma_f32_16x16x32_bf16(a0, b1, acc01, 0, 0, 0);
    acc10 = __builtin_amdgcn_mfma_f32_16x16x32_bf16(a1, b0, acc10, 0, 0, 0);
    acc11 = __builtin_amdgcn_mfma_f32_16x16x32_bf16(a1, b1, acc11, 0, 0, 0);
  }

  float* pc00 = C + (size_t)(tm * 32 + quad * 4) * N + tn * 32 + m;
#pragma unroll
  for (int r = 0; r < 4; ++r) {
    atomicAdd(&pc00[(size_t)r * N],             acc00[r]);
    atomicAdd(&pc00[(size_t)r * N + 16],        acc01[r]);
    atomicAdd(&pc00[(size_t)(r + 16) * N],      acc10[r]);
    atomicAdd(&pc00[(size_t)(r + 16) * N + 16], acc11[r]);
  }
}

// ---------------------------------------------------------------------------
// Attention, work-balanced: block (it,h) owns rows {4it..4it+3} and
// {508-4it..511-4it}. Wave w handles one low row (4it+w) and one high row
// (508-4it+3-w). Local sc rows: low -> w, high -> 7-w.
// ---------------------------------------------------------------------------
__global__ __launch_bounds__(256) void attn_kernel(
    const float* __restrict__ a_g, const float* __restrict__ c_g,
    const float* __restrict__ v_g, const float* __restrict__ b1,
    const float* __restrict__ W2, const float* __restrict__ b2,
    const float* __restrict__ W3, const float* __restrict__ b3,
    short* __restrict__ attnout) {
  const int it = blockIdx.x;           // 0..63
  const int h  = blockIdx.y;
  const int tid = threadIdx.x;
  const int w = tid >> 6;
  const int lane = tid & 63;
  const int m = lane & 15;
  const int quad = lane >> 4;

  const int lo = it * 4;
  const int hi0 = 508 - lo;

  __shared__ float sc[8][N_SEQ];       // 16 KB
  __shared__ float invr[8];

  // W2 A-fragment
  bf16x8 w2f;
  {
    const float4* wp = (const float4*)(W2 + m * P + quad * 8);
    const float4 w0 = wp[0], w1 = wp[1];
    union { bf16x8 v; __hip_bfloat162 h2[4]; } u;
    u.h2[0] = __float22bfloat162_rn(make_float2(w0.x, w0.y));
    u.h2[1] = __float22bfloat162_rn(make_float2(w0.z, w0.w));
    u.h2[2] = __float22bfloat162_rn(make_float2(w1.x, w1.y));
    u.h2[3] = __float22bfloat162_rn(make_float2(w1.z, w1.w));
    w2f = u.v;
  }
  const float4 b2q = *(const float4*)(b2 + quad * 4);
  const float4 w3q = *(const float4*)(W3 + quad * 4);
  const float b3v = b3[0];

  const int gi_lo = lo + w;
  const int gi_hi = hi0 + (3 - w);
  const int rl = w, rh = 7 - w;        // local sc rows
  const int nt_lo = (gi_lo >> 4) + 1;
  const int nt_hi = (gi_hi >> 4) + 1;

  float ab0[8], ab1[8];
  {
    const float4* bp = (const float4*)(b1 + quad * 8);
    const float4 q0 = bp[0], q1 = bp[1];
    const float4* a0p = (const float4*)(a_g + ((size_t)h * N_SEQ + gi_lo) * P + quad * 8);
    const float4* a1p = (const float4*)(a_g + ((size_t)h * N_SEQ + gi_hi) * P + quad * 8);
    const float4 a00 = a0p[0], a01 = a0p[1];
    const float4 a10 = a1p[0], a11 = a1p[1];
    ab0[0] = a00.x + q0.x; ab0[1] = a00.y + q0.y;
    ab0[2] = a00.z + q0.z; ab0[3] = a00.w + q0.w;
    ab0[4] = a01.x + q1.x; ab0[5] = a01.y + q1.y;
    ab0[6] = a01.z + q1.z; ab0[7] = a01.w + q1.w;
    ab1[0] = a10.x + q0.x; ab1[1] = a10.y + q0.y;
    ab1[2] = a10.z + q0.z; ab1[3] = a10.w + q0.w;
    ab1[4] = a11.x + q1.x; ab1[5] = a11.y + q1.y;
    ab1[6] = a11.z + q1.z; ab1[7] = a11.w + q1.w;
  }

  // ---- phase 1: scores ----
#pragma unroll 2
  for (int jt = 0; jt < nt_hi; ++jt) {
    const float4* cp = (const float4*)(c_g + ((size_t)h * N_SEQ + jt * 16 + m) * P + quad * 8);
    const float4 c0 = cp[0], c1 = cp[1];

    union { bf16x8 v; __hip_bfloat162 h2[4]; } u1;
    u1.h2[0] = __float22bfloat162_rn(make_float2(fmaxf(ab1[0] + c0.x, 0.f),
                                                 fmaxf(ab1[1] + c0.y, 0.f)));
    u1.h2[1] = __float22bfloat162_rn(make_float2(fmaxf(ab1[2] + c0.z, 0.f),
                                                 fmaxf(ab1[3] + c0.w, 0.f)));
    u1.h2[2] = __float22bfloat162_rn(make_float2(fmaxf(ab1[4] + c1.x, 0.f),
                                                 fmaxf(ab1[5] + c1.y, 0.f)));
    u1.h2[3] = __float22bfloat162_rn(make_float2(fmaxf(ab1[6] + c1.z, 0.f),
                                                 fmaxf(ab1[7] + c1.w, 0.f)));
    f32x4 acc1 = {0.f,0.f,0.f,0.f};
    acc1 = __builtin_amdgcn_mfma_f32_16x16x32_bf16(w2f, u1.v, acc1, 0, 0, 0);

    if (jt < nt_lo) {
      union { bf16x8 v; __hip_bfloat162 h2[4]; } u0;
      u0.h2[0] = __float22bfloat162_rn(make_float2(fmaxf(ab0[0] + c0.x, 0.f),
                                                   fmaxf(ab0[1] + c0.y, 0.f)));
      u0.h2[1] = __float22bfloat162_rn(make_float2(fmaxf(ab0[2] + c0.z, 0.f),
                                                   fmaxf(ab0[3] + c0.w, 0.f)));
      u0.h2[2] = __float22bfloat162_rn(make_float2(fmaxf(ab0[4] + c1.x, 0.f),
                                                   fmaxf(ab0[5] + c1.y, 0.f)));
      u0.h2[3] = __float22bfloat162_rn(make_float2(fmaxf(ab0[6] + c1.z, 0.f),
                                                   fmaxf(ab0[7] + c1.w, 0.f)));
      f32x4 acc0 = {0.f,0.f,0.f,0.f};
      acc0 = __builtin_amdgcn_mfma_f32_16x16x32_bf16(w2f, u0.v, acc0, 0, 0, 0);
      float t0 = fmaxf(acc0[0] + b2q.x, 0.f) * w3q.x
               + fmaxf(acc0[1] + b2q.y, 0.f) * w3q.y
               + fmaxf(acc0[2] + b2q.z, 0.f) * w3q.z
               + fmaxf(acc0[3] + b2q.w, 0.f) * w3q.w;
      t0 += __shfl_xor(t0, 16); t0 += __shfl_xor(t0, 32);
      if (quad == 0) sc[rl][jt * 16 + m] = t0 + b3v;
    }

    float t1 = fmaxf(acc1[0] + b2q.x, 0.f) * w3q.x
             + fmaxf(acc1[1] + b2q.y, 0.f) * w3q.y
             + fmaxf(acc1[2] + b2q.z, 0.f) * w3q.z
             + fmaxf(acc1[3] + b2q.w, 0.f) * w3q.w;
    t1 += __shfl_xor(t1, 16); t1 += __shfl_xor(t1, 32);
    if (quad == 1) sc[rh][jt * 16 + m] = t1 + b3v;
  }
  __syncthreads();

  // ---- phase 2: per-row softmax, zero-fill to 512 ----
  {
    const int row = tid >> 5, sl = tid & 31;
    const int ig = (row < 4) ? (lo + row) : (hi0 + (row - 4));
    float mx = -1e30f;
    for (int j = sl; j <= ig; j += 32) mx = fmaxf(mx, sc[row][j]);
#pragma unroll
    for (int msk = 1; msk < 32; msk <<= 1) mx = fmaxf(mx, __shfl_xor(mx, msk));
    float sum = 0.f;
    for (int j = sl; j < N_SEQ; j += 32) {
      const float e = (j <= ig) ? __expf(sc[row][j] - mx) : 0.f;
      sc[row][j] = e;
      sum += e;
    }
#pragma unroll
    for (int msk = 1; msk < 32; msk <<= 1) sum += __shfl_xor(sum, msk);
    if (sl == 0) invr[row] = 1.f / sum;
  }
  __syncthreads();

  // ---- phase 3: attn @ V, V loads shared by the wave's two rows ----
  {
    const int jj = lane >> 4;
    const int dg = m;
    const float4* vp = (const float4*)(v_g + (size_t)h * N_SEQ * DH);
    float4 A0 = {0.f,0.f,0.f,0.f}, A1 = {0.f,0.f,0.f,0.f};
    for (int j = jj; j <= gi_hi; j += 4) {
      const float4 v4 = vp[(size_t)j * 16 + dg];
      const float s0 = sc[rl][j];   // 0 beyond gi_lo
      const float s1 = sc[rh][j];
      A0.x += s0 * v4.x; A0.y += s0 * v4.y; A0.z += s0 * v4.z; A0.w += s0 * v4.w;
      A1.x += s1 * v4.x; A1.y += s1 * v4.y; A1.z += s1 * v4.z; A1.w += s1 * v4.w;
    }
#pragma unroll
    for (int msk = 16; msk < 64; msk <<= 1) {
      A0.x += __shfl_xor(A0.x, msk); A0.y += __shfl_xor(A0.y, msk);
      A0.z += __shfl_xor(A0.z, msk); A0.w += __shfl_xor(A0.w, msk);
      A1.x += __shfl_xor(A1.x, msk); A1.y += __shfl_xor(A1.y, msk);
      A1.z += __shfl_xor(A1.z, msk); A1.w += __shfl_xor(A1.w, msk);
    }
    if (jj == 0) {
      const float inv0 = invr[rl], inv1 = invr[rh];
      ushort4 o0, o1;
      o0.x = f2bf(A0.x * inv0); o0.y = f2bf(A0.y * inv0);
      o0.z = f2bf(A0.z * inv0); o0.w = f2bf(A0.w * inv0);
      o1.x = f2bf(A1.x * inv1); o1.y = f2bf(A1.y * inv1);
      o1.z = f2bf(A1.z * inv1); o1.w = f2bf(A1.w * inv1);
      *(ushort4*)(attnout + (size_t)gi_lo * DIM + h * DH + dg * 4) = o0;
      *(ushort4*)(attnout + (size_t)gi_hi * DIM + h * DH + dg * 4) = o1;
    }
  }
}

// ---------------------------------------------------------------------------
extern "C" void kernel_launch(void* const* d_in, const int* in_sizes, int n_in,
                              void* d_out, int out_size, void* d_ws, size_t ws_size,
                              hipStream_t stream) {
  const float* x    = (const float*)d_in[0];
  const float* Wqkv = (const float*)d_in[1];
  const float* Wout = (const float*)d_in[2];
  const float* Wq   = (const float*)d_in[3];
  const float* bq   = (const float*)d_in[4];
  const float* Wk   = (const float*)d_in[5];
  const float* bk   = (const float*)d_in[6];
  const float* W1   = (const float*)d_in[7];
  const float* b1   = (const float*)d_in[8];
  const float* W2   = (const float*)d_in[9];
  const float* b2   = (const float*)d_in[10];
  const float* W3   = (const float*)d_in[11];
  const float* b3   = (const float*)d_in[12];
  float* out = (float*)d_out;

  float* ws    = (float*)d_ws;
  float* a_buf = ws;                                   // 16*512*32
  float* c_buf = a_buf + (size_t)HEADS * N_SEQ * P;    // 16*512*32
  float* v_buf = c_buf + (size_t)HEADS * N_SEQ * P;    // 16*512*64
  float* Wa    = v_buf + (size_t)HEADS * N_SEQ * DH;   // 32*64
  float* Wc    = Wa + 2048;                            // 32*64
  float* ba32  = Wc + 2048;                            // 32
  float* bc32  = ba32 + 32;                            // 32
  short* Wcomb = (short*)(bc32 + 32);                  // 2048*1024 bf16
  short* xb    = Wcomb + (size_t)2048 * DIM;           // 512*1024 bf16
  short* Woutb = xb + (size_t)N_SEQ * DIM;             // 1024*1024 bf16
  short* attnb = Woutb + (size_t)DIM * DIM;            // 512*1024 bf16

  // 0) zero split-K accumulator for the output GEMM
  hipMemsetAsync(out, 0, (size_t)N_SEQ * DIM * sizeof(float), stream);

  // 1) small folded weights
  prep_small<<<1, 256, 0, stream>>>(Wq, bq, Wk, bk, W1, Wa, Wc, ba32, bc32);

  // 2) bf16 casts of x and Wout
  {
    const int n0 = (N_SEQ * DIM) / 4;
    const int n1 = (DIM * DIM) / 4;
    cvt3_bf16<<<(n0 + n1 + 255) / 256, 256, 0, stream>>>(
        (const float4*)x,    (ushort4*)xb,    n0,
        (const float4*)Wout, (ushort4*)Woutb, n1,
        (const float4*)x,    (ushort4*)xb,    0);
  }

  // 3) build Wcomb (a/c folded rows + permuted v rows)
  prep_big<<<512, 256, 0, stream>>>(Wqkv, Wa, Wc, Wcomb);

  // 4) main GEMM -> a_buf, c_buf, v_buf (with folded biases)
  gemm_acv<<<512, 256, 0, stream>>>(xb, Wcomb, ba32, bc32,
                                    a_buf, c_buf, v_buf);

  // 5) balanced attention
  dim3 g3(N_SEQ / 8, HEADS);
  attn_kernel<<<g3, 256, 0, stream>>>(a_buf, c_buf, v_buf, b1, W2, b2, W3, b3,
                                      attnb);

  // 6) output GEMM (split-K 4)
  {
    const int waves = (N_SEQ / 32) * (DIM / 32) * 4;
    gemm_mfma_nt2<4><<<waves / 4, 256, 0, stream>>>(attnb, Woutb, out,
                                                    N_SEQ, DIM, DIM);
  }
}

// Round 7
// 177.982 us; speedup vs baseline: 3.3233x; 1.1526x over previous
//
#include <hip/hip_runtime.h>
#include <hip/hip_bf16.h>
#include <hip/hip_fp16.h>
#include <math.h>

#define N_SEQ 512
#define DIM   1024
#define HEADS 16
#define DH    64
#define P     32
#define P2    16

typedef short    bf16x8 __attribute__((ext_vector_type(8)));
typedef _Float16 f16x8  __attribute__((ext_vector_type(8)));
typedef float    f32x4  __attribute__((ext_vector_type(4)));

__device__ inline unsigned short f2bf(float f) {
  union { float f; unsigned u; } v; v.f = f;
  unsigned r = (v.u + 0x7fffu + ((v.u >> 16) & 1u)) >> 16;
  return (unsigned short)r;
}

union H8 { f16x8 v; __half2 h2[4]; unsigned u32[4]; };

// ---------------------------------------------------------------------------
// Fused prep: 768 blocks.
//  [0,256):  fold Wa=W1q@Wq (or Wc=W1k@Wk) in-block, then Wcomb a/c rows;
//            blocks 0 and 128 also emit ba32/bc32.
//  [256,384): Wcomb v-rows (bf16 cast of permuted Wqkv rows).
//  [384,512): x -> bf16.   [512,768): Wout -> bf16.
// ---------------------------------------------------------------------------
__global__ __launch_bounds__(256) void prep(
    const float* __restrict__ Wqkv, const float* __restrict__ Wq,
    const float* __restrict__ bq, const float* __restrict__ Wk,
    const float* __restrict__ bk, const float* __restrict__ W1,
    const float* __restrict__ x, const float* __restrict__ Wout,
    short* __restrict__ Wcomb, short* __restrict__ xb,
    short* __restrict__ Woutb, float* __restrict__ ba32,
    float* __restrict__ bc32) {
  const int b = blockIdx.x, tid = threadIdx.x;
  if (b < 256) {
    __shared__ float W1s[32][33];
    __shared__ float Wqs[32][65];
    __shared__ float wsm[32][65];
    __shared__ __align__(16) float qs[64][132];
    const int part = b >> 7, rem = b & 127;
    const int h = rem >> 3, c0 = (rem & 7) * 128;
    const int grow = part * 16 + h;
    for (int idx = tid; idx < 1024; idx += 256)
      W1s[idx >> 5][idx & 31] = W1[(idx >> 5) * 64 + part * 32 + (idx & 31)];
    const float* Wsel = part ? Wk : Wq;
    for (int idx = tid; idx < 2048; idx += 256)
      Wqs[idx >> 6][idx & 63] = Wsel[idx];
    for (int idx = tid; idx < 2048; idx += 256) {
      const int d = idx >> 5, c4 = idx & 31;
      *(float4*)&qs[d][c4 * 4] =
          *(const float4*)(Wqkv + (size_t)(d * 48 + grow) * DIM + c0 + c4 * 4);
    }
    __syncthreads();
    for (int idx = tid; idx < 2048; idx += 256) {
      const int q = idx >> 6, d = idx & 63;
      float s = 0.f;
#pragma unroll
      for (int p = 0; p < 32; ++p) s += W1s[q][p] * Wqs[p][d];
      wsm[q][d] = s;
    }
    __syncthreads();
    for (int idx = tid; idx < 4096; idx += 256) {
      const int q = idx >> 7, c = idx & 127;
      float s = 0.f;
#pragma unroll
      for (int d = 0; d < 64; ++d) s += wsm[q][d] * qs[d][c];
      Wcomb[(size_t)(part * 512 + h * 32 + q) * DIM + c0 + c] = (short)f2bf(s);
    }
    if (rem == 0 && tid < 32) {
      const float* bsel = part ? bk : bq;
      float s = 0.f;
#pragma unroll
      for (int p = 0; p < 32; ++p) s += W1s[tid][p] * bsel[p];
      (part ? bc32 : ba32)[tid] = s;
    }
  } else if (b < 384) {
#pragma unroll
    for (int rr = 0; rr < 8; ++rr) {
      const int ov = (b - 256) * 8 + rr;
      const int h = ov >> 6, d = ov & 63;
      const float4 v = *(const float4*)(Wqkv + (size_t)(d * 48 + 32 + h) * DIM + tid * 4);
      ushort4 o;
      o.x = f2bf(v.x); o.y = f2bf(v.y); o.z = f2bf(v.z); o.w = f2bf(v.w);
      *(ushort4*)(Wcomb + (size_t)(1024 + ov) * DIM + tid * 4) = o;
    }
  } else if (b < 512) {
    const int idx = (b - 384) * 256 + tid;       // 32768 threads, 131072 float4
#pragma unroll
    for (int u = 0; u < 4; ++u) {
      const int t = u * 32768 + idx;
      const float4 v = ((const float4*)x)[t];
      ushort4 o;
      o.x = f2bf(v.x); o.y = f2bf(v.y); o.z = f2bf(v.z); o.w = f2bf(v.w);
      ((ushort4*)xb)[t] = o;
    }
  } else {
    const int idx = (b - 512) * 256 + tid;       // 65536 threads, 262144 float4
#pragma unroll
    for (int u = 0; u < 4; ++u) {
      const int t = u * 65536 + idx;
      const float4 v = ((const float4*)Wout)[t];
      ushort4 o;
      o.x = f2bf(v.x); o.y = f2bf(v.y); o.z = f2bf(v.z); o.w = f2bf(v.w);
      ((ushort4*)Woutb)[t] = o;
    }
  }
}

// ---------------------------------------------------------------------------
// Main GEMM: Y(512x2048) = xb @ Wcomb^T; scatter to fp16 a / cb(+b1) / vT.
// 16x32 tile per wave, 2048 waves = 512 blocks.
// ---------------------------------------------------------------------------
__global__ __launch_bounds__(256) void gemm_acv(
    const short* __restrict__ xb, const short* __restrict__ Wcomb,
    const float* __restrict__ ba32, const float* __restrict__ bc32,
    const float* __restrict__ b1,
    __half* __restrict__ a_buf, __half* __restrict__ cb_buf,
    __half* __restrict__ vT) {
  const int wave = blockIdx.x * 4 + (threadIdx.x >> 6);
  const int tm = wave >> 6;          // 0..31
  const int tn = wave & 63;          // 0..63
  const int lane = threadIdx.x & 63;
  const int m = lane & 15;
  const int quad = lane >> 4;

  const short* pa  = xb + (size_t)(tm * 16 + m) * DIM + quad * 8;
  const short* pb0 = Wcomb + (size_t)(tn * 32 + m) * DIM + quad * 8;
  const short* pb1 = pb0 + (size_t)16 * DIM;

  f32x4 acc0 = {0.f,0.f,0.f,0.f}, acc1 = {0.f,0.f,0.f,0.f};
#pragma unroll 4
  for (int k = 0; k < DIM; k += 32) {
    const bf16x8 av = *(const bf16x8*)(pa + k);
    const bf16x8 b0 = *(const bf16x8*)(pb0 + k);
    const bf16x8 b1v = *(const bf16x8*)(pb1 + k);
    acc0 = __builtin_amdgcn_mfma_f32_16x16x32_bf16(av, b0, acc0, 0, 0, 0);
    acc1 = __builtin_amdgcn_mfma_f32_16x16x32_bf16(av, b1v, acc1, 0, 0, 0);
  }

#pragma unroll
  for (int r = 0; r < 4; ++r) {
    const int n = tm * 16 + quad * 4 + r;
#pragma unroll
    for (int half = 0; half < 2; ++half) {
      const int o = tn * 32 + m + half * 16;
      const float val = half ? acc1[r] : acc0[r];
      if (o < 512) {
        const int h = o >> 5, q = o & 31;
        a_buf[((size_t)h * N_SEQ + n) * P + q] = __float2half(val + ba32[q]);
      } else if (o < 1024) {
        const int oo = o - 512, h = oo >> 5, q = oo & 31;
        cb_buf[((size_t)h * N_SEQ + n) * P + q] = __float2half(val + bc32[q] + b1[q]);
      } else {
        const int ov = o - 1024, h = ov >> 6, d = ov & 63;
        vT[((size_t)h * DH + d) * N_SEQ + n] = __float2half(val);
      }
    }
  }
}

// ---------------------------------------------------------------------------
// Scores + softmax -> prob fp16. One wave per block; 4 rows:
// {2it, 2it+1, 510-2it, 511-2it} (mirror-balanced). fp16 h1 build,
// mfma f16 (D[q][j]), 3-shfl 4x4 transpose-reduce across quads.
// ---------------------------------------------------------------------------
__device__ inline float rowscore(const H8& a, const H8& c, f16x8 w2f,
                                 float4 b2q, float4 w3q) {
  H8 u;
#pragma unroll
  for (int k = 0; k < 4; ++k) {
    const __half2 s = __hadd2(a.h2[k], c.h2[k]);
    union { __half2 h; unsigned u; } cv; cv.h = s;
    const unsigned msk = (cv.u >> 15) & 0x00010001u;   // sign bits
    u.u32[k] = cv.u & ~(msk * 0xFFFFu);                // packed relu
  }
  f32x4 acc = {0.f, 0.f, 0.f, 0.f};
  acc = __builtin_amdgcn_mfma_f32_16x16x32_f16(w2f, u.v, acc, 0, 0, 0);
  return fmaxf(acc[0] + b2q.x, 0.f) * w3q.x + fmaxf(acc[1] + b2q.y, 0.f) * w3q.y
       + fmaxf(acc[2] + b2q.z, 0.f) * w3q.z + fmaxf(acc[3] + b2q.w, 0.f) * w3q.w;
}

__global__ __launch_bounds__(64) void attn_score(
    const __half* __restrict__ a_g, const __half* __restrict__ cb_g,
    const float* __restrict__ W2, const float* __restrict__ b2,
    const float* __restrict__ W3, const float* __restrict__ b3,
    __half* __restrict__ prob) {
  const int it = blockIdx.x;           // 0..127
  const int h  = blockIdx.y;
  const int lane = threadIdx.x;
  const int m = lane & 15, quad = lane >> 4;

  __shared__ __align__(16) float sc[4][528];   // stride 528 => 2-way max banks

  const int r0 = 2 * it, r1 = 2 * it + 1;
  const int r2 = 510 - 2 * it, r3 = 511 - 2 * it;
  const int n0 = (r0 >> 4) + 1, n1 = (r1 >> 4) + 1;
  const int n2 = (r2 >> 4) + 1, n3 = (r3 >> 4) + 1;
  const int ntq = (quad == 0) ? n0 : (quad == 1) ? n1 : (quad == 2) ? n2 : n3;

  // W2 fp16 A-fragment: A[q=m][p=quad*8+j]
  f16x8 w2f;
  {
    const float4* wp = (const float4*)(W2 + m * P + quad * 8);
    const float4 w0 = wp[0], w1 = wp[1];
    H8 u;
    u.h2[0] = __floats2half2_rn(w0.x, w0.y);
    u.h2[1] = __floats2half2_rn(w0.z, w0.w);
    u.h2[2] = __floats2half2_rn(w1.x, w1.y);
    u.h2[3] = __floats2half2_rn(w1.z, w1.w);
    w2f = u.v;
  }
  const float4 b2q = *(const float4*)(b2 + quad * 4);
  const float4 w3q = *(const float4*)(W3 + quad * 4);
  const float b3v = b3[0];

  H8 a0, a1, a2, a3;
  a0.v = *(const f16x8*)(a_g + ((size_t)h * N_SEQ + r0) * P + quad * 8);
  a1.v = *(const f16x8*)(a_g + ((size_t)h * N_SEQ + r1) * P + quad * 8);
  a2.v = *(const f16x8*)(a_g + ((size_t)h * N_SEQ + r2) * P + quad * 8);
  a3.v = *(const f16x8*)(a_g + ((size_t)h * N_SEQ + r3) * P + quad * 8);

  float p0 = 0.f, p1 = 0.f, p2 = 0.f, p3 = 0.f;
  for (int jt = 0; jt < n3; ++jt) {
    H8 cb;
    cb.v = *(const f16x8*)(cb_g + ((size_t)h * N_SEQ + jt * 16 + m) * P + quad * 8);
    p3 = rowscore(a3, cb, w2f, b2q, w3q);
    if (jt < n2) p2 = rowscore(a2, cb, w2f, b2q, w3q);
    if (jt < n1) p1 = rowscore(a1, cb, w2f, b2q, w3q);
    if (jt < n0) p0 = rowscore(a0, cb, w2f, b2q, w3q);

    // 4x4 transpose-reduce across quads (3 shfl): quad r ends with sum of p_r
    const float sx = (quad & 1) ? p0 : p1;
    const float sy = (quad & 1) ? p2 : p3;
    const float rx = __shfl_xor(sx, 16);
    const float ry = __shfl_xor(sy, 16);
    const float aa = ((quad & 1) ? p1 : p0) + rx;   // row (quad&1), pair {q,q^1}
    const float bb = ((quad & 1) ? p3 : p2) + ry;   // row 2+(quad&1)
    const float sz = (quad & 2) ? aa : bb;
    const float rz = __shfl_xor(sz, 32);
    const float fin = ((quad & 2) ? bb : aa) + rz;

    if (jt < ntq) sc[quad][jt * 16 + m] = fin + b3v;
  }
  __syncthreads();

  // per-row softmax + fp16 prob write (zero beyond causal limit)
  const int base = lane * 8;
#pragma unroll
  for (int r = 0; r < 4; ++r) {
    const int rq = (r == 0) ? r0 : (r == 1) ? r1 : (r == 2) ? r2 : r3;
    float v[8];
    *(float4*)&v[0] = *(const float4*)&sc[r][base];
    *(float4*)&v[4] = *(const float4*)&sc[r][base + 4];
    float mx = -1e30f;
#pragma unroll
    for (int u = 0; u < 8; ++u) if (base + u <= rq) mx = fmaxf(mx, v[u]);
#pragma unroll
    for (int msk = 1; msk < 64; msk <<= 1) mx = fmaxf(mx, __shfl_xor(mx, msk));
    float e[8], sum = 0.f;
#pragma unroll
    for (int u = 0; u < 8; ++u) {
      e[u] = (base + u <= rq) ? __expf(v[u] - mx) : 0.f;
      sum += e[u];
    }
#pragma unroll
    for (int msk = 1; msk < 64; msk <<= 1) sum += __shfl_xor(sum, msk);
    const float inv = 1.f / sum;
    H8 o;
    o.h2[0] = __floats2half2_rn(e[0] * inv, e[1] * inv);
    o.h2[1] = __floats2half2_rn(e[2] * inv, e[3] * inv);
    o.h2[2] = __floats2half2_rn(e[4] * inv, e[5] * inv);
    o.h2[3] = __floats2half2_rn(e[6] * inv, e[7] * inv);
    *(f16x8*)(prob + ((size_t)h * N_SEQ + rq) * N_SEQ + base) = o.v;
  }
}

// ---------------------------------------------------------------------------
// attn @ V as per-head causal-trimmed MFMA GEMM:
// attnb[i][h*64+d] = sum_j prob[h][i][j] * vT[h][d][j].  16x16 tile/wave.
// ---------------------------------------------------------------------------
__global__ __launch_bounds__(256) void attn_pv(
    const __half* __restrict__ prob, const __half* __restrict__ vT,
    short* __restrict__ attnb) {
  const int wave = blockIdx.x * 4 + (threadIdx.x >> 6);   // 0..2047
  const int h = wave >> 7;
  const int rem = wave & 127;
  const int tm = rem >> 2;          // 0..31 (i-tile)
  const int tn = rem & 3;           // 0..3  (d-tile)
  const int lane = threadIdx.x & 63;
  const int m = lane & 15, quad = lane >> 4;

  const __half* pa = prob + ((size_t)h * N_SEQ + tm * 16 + m) * N_SEQ + quad * 8;
  const __half* pb = vT + ((size_t)h * DH + tn * 16 + m) * N_SEQ + quad * 8;

  f32x4 acc = {0.f, 0.f, 0.f, 0.f};
  const int kmax = tm * 16 + 16;    // causal trim (prob zero beyond i)
  for (int k = 0; k < kmax; k += 32) {
    const f16x8 a = *(const f16x8*)(pa + k);
    const f16x8 b = *(const f16x8*)(pb + k);
    acc = __builtin_amdgcn_mfma_f32_16x16x32_f16(a, b, acc, 0, 0, 0);
  }
#pragma unroll
  for (int r = 0; r < 4; ++r)
    attnb[(size_t)(tm * 16 + quad * 4 + r) * DIM + h * DH + tn * 16 + m] =
        (short)f2bf(acc[r]);
}

// ---------------------------------------------------------------------------
// Output GEMM: out(512x1024) = attnb @ Woutb^T. 16x16 tile/wave, 512 blocks.
// ---------------------------------------------------------------------------
__global__ __launch_bounds__(256) void gemm_out16(
    const short* __restrict__ A, const short* __restrict__ B,
    float* __restrict__ C) {
  const int wave = blockIdx.x * 4 + (threadIdx.x >> 6);   // 0..2047
  const int tm = wave >> 6;         // 0..31
  const int tn = wave & 63;         // 0..63
  const int lane = threadIdx.x & 63;
  const int m = lane & 15, quad = lane >> 4;

  const short* pa = A + (size_t)(tm * 16 + m) * DIM + quad * 8;
  const short* pb = B + (size_t)(tn * 16 + m) * DIM + quad * 8;

  f32x4 acc = {0.f, 0.f, 0.f, 0.f};
#pragma unroll 4
  for (int k = 0; k < DIM; k += 32) {
    const bf16x8 a = *(const bf16x8*)(pa + k);
    const bf16x8 b = *(const bf16x8*)(pb + k);
    acc = __builtin_amdgcn_mfma_f32_16x16x32_bf16(a, b, acc, 0, 0, 0);
  }
#pragma unroll
  for (int r = 0; r < 4; ++r)
    C[(size_t)(tm * 16 + quad * 4 + r) * DIM + tn * 16 + m] = acc[r];
}

// ---------------------------------------------------------------------------
extern "C" void kernel_launch(void* const* d_in, const int* in_sizes, int n_in,
                              void* d_out, int out_size, void* d_ws, size_t ws_size,
                              hipStream_t stream) {
  const float* x    = (const float*)d_in[0];
  const float* Wqkv = (const float*)d_in[1];
  const float* Wout = (const float*)d_in[2];
  const float* Wq   = (const float*)d_in[3];
  const float* bq   = (const float*)d_in[4];
  const float* Wk   = (const float*)d_in[5];
  const float* bk   = (const float*)d_in[6];
  const float* W1   = (const float*)d_in[7];
  const float* b1   = (const float*)d_in[8];
  const float* W2   = (const float*)d_in[9];
  const float* b2   = (const float*)d_in[10];
  const float* W3   = (const float*)d_in[11];
  const float* b3   = (const float*)d_in[12];
  float* out = (float*)d_out;

  float*  ws     = (float*)d_ws;
  float*  ba32   = ws;                                   // 32
  float*  bc32   = ba32 + 32;                            // 32
  __half* a_buf  = (__half*)(bc32 + 32);                 // 16*512*32
  __half* cb_buf = a_buf + (size_t)HEADS * N_SEQ * P;    // 16*512*32
  __half* vT     = cb_buf + (size_t)HEADS * N_SEQ * P;   // 16*64*512
  __half* prob   = vT + (size_t)HEADS * DH * N_SEQ;      // 16*512*512
  short*  Wcomb  = (short*)(prob + (size_t)HEADS * N_SEQ * N_SEQ); // 2048*1024
  short*  xb     = Wcomb + (size_t)2048 * DIM;           // 512*1024
  short*  Woutb  = xb + (size_t)N_SEQ * DIM;             // 1024*1024
  short*  attnb  = Woutb + (size_t)DIM * DIM;            // 512*1024

  // 1) fused prep: weight folding + all bf16 casts
  prep<<<768, 256, 0, stream>>>(Wqkv, Wq, bq, Wk, bk, W1, x, Wout,
                                Wcomb, xb, Woutb, ba32, bc32);

  // 2) main GEMM -> fp16 a / cb(+b1) / vT
  gemm_acv<<<512, 256, 0, stream>>>(xb, Wcomb, ba32, bc32, b1,
                                    a_buf, cb_buf, vT);

  // 3) scores + softmax -> prob fp16 (mirror-balanced, 1 wave / 4 rows)
  dim3 g3(128, HEADS);
  attn_score<<<g3, 64, 0, stream>>>(a_buf, cb_buf, W2, b2, W3, b3, prob);

  // 4) prob @ V (per-head MFMA GEMM, causal-trimmed)
  attn_pv<<<512, 256, 0, stream>>>(prob, vT, attnb);

  // 5) output GEMM
  gemm_out16<<<512, 256, 0, stream>>>(attnb, Woutb, out);
}

// Round 8
// 174.144 us; speedup vs baseline: 3.3965x; 1.0220x over previous
//
#include <hip/hip_runtime.h>
#include <hip/hip_bf16.h>
#include <hip/hip_fp16.h>
#include <math.h>

#define N_SEQ 512
#define DIM   1024
#define HEADS 16
#define DH    64
#define P     32
#define P2    16
#define PSTR  520   // prob LDS row stride in halfs (2-way banks, 16B aligned)

typedef short    bf16x8 __attribute__((ext_vector_type(8)));
typedef _Float16 f16x8  __attribute__((ext_vector_type(8)));
typedef float    f32x4  __attribute__((ext_vector_type(4)));

__device__ inline unsigned short f2bf(float f) {
  union { float f; unsigned u; } v; v.f = f;
  unsigned r = (v.u + 0x7fffu + ((v.u >> 16) & 1u)) >> 16;
  return (unsigned short)r;
}

union H8 { f16x8 v; __half2 h2[4]; unsigned u32[4]; };

// ---------------------------------------------------------------------------
// Fused prep (same as R7): weight folding + all bf16 casts. 768 blocks.
// ---------------------------------------------------------------------------
__global__ __launch_bounds__(256) void prep(
    const float* __restrict__ Wqkv, const float* __restrict__ Wq,
    const float* __restrict__ bq, const float* __restrict__ Wk,
    const float* __restrict__ bk, const float* __restrict__ W1,
    const float* __restrict__ x, const float* __restrict__ Wout,
    short* __restrict__ Wcomb, short* __restrict__ xb,
    short* __restrict__ Woutb, float* __restrict__ ba32,
    float* __restrict__ bc32) {
  const int b = blockIdx.x, tid = threadIdx.x;
  if (b < 256) {
    __shared__ float W1s[32][33];
    __shared__ float Wqs[32][65];
    __shared__ float wsm[32][65];
    __shared__ __align__(16) float qs[64][132];
    const int part = b >> 7, rem = b & 127;
    const int h = rem >> 3, c0 = (rem & 7) * 128;
    const int grow = part * 16 + h;
    for (int idx = tid; idx < 1024; idx += 256)
      W1s[idx >> 5][idx & 31] = W1[(idx >> 5) * 64 + part * 32 + (idx & 31)];
    const float* Wsel = part ? Wk : Wq;
    for (int idx = tid; idx < 2048; idx += 256)
      Wqs[idx >> 6][idx & 63] = Wsel[idx];
    for (int idx = tid; idx < 2048; idx += 256) {
      const int d = idx >> 5, c4 = idx & 31;
      *(float4*)&qs[d][c4 * 4] =
          *(const float4*)(Wqkv + (size_t)(d * 48 + grow) * DIM + c0 + c4 * 4);
    }
    __syncthreads();
    for (int idx = tid; idx < 2048; idx += 256) {
      const int q = idx >> 6, d = idx & 63;
      float s = 0.f;
#pragma unroll
      for (int p = 0; p < 32; ++p) s += W1s[q][p] * Wqs[p][d];
      wsm[q][d] = s;
    }
    __syncthreads();
    for (int idx = tid; idx < 4096; idx += 256) {
      const int q = idx >> 7, c = idx & 127;
      float s = 0.f;
#pragma unroll
      for (int d = 0; d < 64; ++d) s += wsm[q][d] * qs[d][c];
      Wcomb[(size_t)(part * 512 + h * 32 + q) * DIM + c0 + c] = (short)f2bf(s);
    }
    if (rem == 0 && tid < 32) {
      const float* bsel = part ? bk : bq;
      float s = 0.f;
#pragma unroll
      for (int p = 0; p < 32; ++p) s += W1s[tid][p] * bsel[p];
      (part ? bc32 : ba32)[tid] = s;
    }
  } else if (b < 384) {
#pragma unroll
    for (int rr = 0; rr < 8; ++rr) {
      const int ov = (b - 256) * 8 + rr;
      const int h = ov >> 6, d = ov & 63;
      const float4 v = *(const float4*)(Wqkv + (size_t)(d * 48 + 32 + h) * DIM + tid * 4);
      ushort4 o;
      o.x = f2bf(v.x); o.y = f2bf(v.y); o.z = f2bf(v.z); o.w = f2bf(v.w);
      *(ushort4*)(Wcomb + (size_t)(1024 + ov) * DIM + tid * 4) = o;
    }
  } else if (b < 512) {
    const int idx = (b - 384) * 256 + tid;
#pragma unroll
    for (int u = 0; u < 4; ++u) {
      const int t = u * 32768 + idx;
      const float4 v = ((const float4*)x)[t];
      ushort4 o;
      o.x = f2bf(v.x); o.y = f2bf(v.y); o.z = f2bf(v.z); o.w = f2bf(v.w);
      ((ushort4*)xb)[t] = o;
    }
  } else {
    const int idx = (b - 512) * 256 + tid;
#pragma unroll
    for (int u = 0; u < 4; ++u) {
      const int t = u * 65536 + idx;
      const float4 v = ((const float4*)Wout)[t];
      ushort4 o;
      o.x = f2bf(v.x); o.y = f2bf(v.y); o.z = f2bf(v.z); o.w = f2bf(v.w);
      ((ushort4*)Woutb)[t] = o;
    }
  }
}

// ---------------------------------------------------------------------------
// Main GEMM: Y(512x2048) = xb @ Wcomb^T; scatter to fp16 a / cb(+b1) / vT.
// ---------------------------------------------------------------------------
__global__ __launch_bounds__(256) void gemm_acv(
    const short* __restrict__ xb, const short* __restrict__ Wcomb,
    const float* __restrict__ ba32, const float* __restrict__ bc32,
    const float* __restrict__ b1,
    __half* __restrict__ a_buf, __half* __restrict__ cb_buf,
    __half* __restrict__ vT) {
  const int wave = blockIdx.x * 4 + (threadIdx.x >> 6);
  const int tm = wave >> 6;
  const int tn = wave & 63;
  const int lane = threadIdx.x & 63;
  const int m = lane & 15;
  const int quad = lane >> 4;

  const short* pa  = xb + (size_t)(tm * 16 + m) * DIM + quad * 8;
  const short* pb0 = Wcomb + (size_t)(tn * 32 + m) * DIM + quad * 8;
  const short* pb1 = pb0 + (size_t)16 * DIM;

  f32x4 acc0 = {0.f,0.f,0.f,0.f}, acc1 = {0.f,0.f,0.f,0.f};
#pragma unroll 4
  for (int k = 0; k < DIM; k += 32) {
    const bf16x8 av = *(const bf16x8*)(pa + k);
    const bf16x8 b0 = *(const bf16x8*)(pb0 + k);
    const bf16x8 b1v = *(const bf16x8*)(pb1 + k);
    acc0 = __builtin_amdgcn_mfma_f32_16x16x32_bf16(av, b0, acc0, 0, 0, 0);
    acc1 = __builtin_amdgcn_mfma_f32_16x16x32_bf16(av, b1v, acc1, 0, 0, 0);
  }

#pragma unroll
  for (int r = 0; r < 4; ++r) {
    const int n = tm * 16 + quad * 4 + r;
#pragma unroll
    for (int half = 0; half < 2; ++half) {
      const int o = tn * 32 + m + half * 16;
      const float val = half ? acc1[r] : acc0[r];
      if (o < 512) {
        const int h = o >> 5, q = o & 31;
        a_buf[((size_t)h * N_SEQ + n) * P + q] = __float2half(val + ba32[q]);
      } else if (o < 1024) {
        const int oo = o - 512, h = oo >> 5, q = oo & 31;
        cb_buf[((size_t)h * N_SEQ + n) * P + q] = __float2half(val + bc32[q] + b1[q]);
      } else {
        const int ov = o - 1024, h = ov >> 6, d = ov & 63;
        vT[((size_t)h * DH + d) * N_SEQ + n] = __float2half(val);
      }
    }
  }
}

// ---------------------------------------------------------------------------
// Fused attention: scores (MFMA) -> softmax (unnorm exp in LDS) -> PV (MFMA).
// Block = (pair p, head): i-tiles {p, 31-p} (16 rows each, mirror-balanced).
// 256 blocks x 256 threads. b3 dropped (cancels in softmax).
// ---------------------------------------------------------------------------
__device__ inline float rowscore(const H8& a, const H8& c, f16x8 w2f,
                                 float4 b2q, float4 w3q) {
  H8 u;
#pragma unroll
  for (int k = 0; k < 4; ++k) {
    const __half2 s = __hadd2(a.h2[k], c.h2[k]);
    union { __half2 h; unsigned u; } cv; cv.h = s;
    const unsigned msk = (cv.u >> 15) & 0x00010001u;
    u.u32[k] = cv.u & ~(msk * 0xFFFFu);          // packed relu
  }
  f32x4 acc = {0.f, 0.f, 0.f, 0.f};
  acc = __builtin_amdgcn_mfma_f32_16x16x32_f16(w2f, u.v, acc, 0, 0, 0);
  return fmaxf(acc[0] + b2q.x, 0.f) * w3q.x + fmaxf(acc[1] + b2q.y, 0.f) * w3q.y
       + fmaxf(acc[2] + b2q.z, 0.f) * w3q.z + fmaxf(acc[3] + b2q.w, 0.f) * w3q.w;
}

__device__ inline float quadreduce4(float p0, float p1, float p2, float p3,
                                    int quad) {
  // 3-shfl 4x4 transpose-reduce: quad q returns sum over quads of p_q.
  const float sx = (quad & 1) ? p0 : p1;
  const float sy = (quad & 1) ? p2 : p3;
  const float rx = __shfl_xor(sx, 16);
  const float ry = __shfl_xor(sy, 16);
  const float aa = ((quad & 1) ? p1 : p0) + rx;
  const float bb = ((quad & 1) ? p3 : p2) + ry;
  const float sz = (quad & 2) ? aa : bb;
  const float rz = __shfl_xor(sz, 32);
  return ((quad & 2) ? bb : aa) + rz;
}

__global__ __launch_bounds__(256) void attn_fused(
    const __half* __restrict__ a_g, const __half* __restrict__ cb_g,
    const float* __restrict__ W2, const float* __restrict__ b2,
    const float* __restrict__ W3,
    const __half* __restrict__ vT, short* __restrict__ attnb) {
  const int p = blockIdx.x;            // 0..15
  const int h = blockIdx.y;
  const int tid = threadIdx.x;
  const int w = tid >> 6;
  const int lane = tid & 63;
  const int m = lane & 15, quad = lane >> 4;

  __shared__ __align__(16) __half probS[32][PSTR];   // 33.3 KB
  __shared__ float invS[32];

  const int tlo = p, thi = 31 - p;
  const int nlo = p + 1, nhi = 32 - p;               // j-tiles per i-tile

  // ---- phase 1: scores -> probS (f16, raw scores) ----
  {
    f16x8 w2f;
    {
      const float4* wp = (const float4*)(W2 + m * P + quad * 8);
      const float4 w0 = wp[0], w1 = wp[1];
      H8 u;
      u.h2[0] = __floats2half2_rn(w0.x, w0.y);
      u.h2[1] = __floats2half2_rn(w0.z, w0.w);
      u.h2[2] = __floats2half2_rn(w1.x, w1.y);
      u.h2[3] = __floats2half2_rn(w1.z, w1.w);
      w2f = u.v;
    }
    const float4 b2q = *(const float4*)(b2 + quad * 4);
    const float4 w3q = *(const float4*)(W3 + quad * 4);

    // wave w owns rows 4w..4w+3 of each tile
    H8 alo[4], ahi[4];
#pragma unroll
    for (int r = 0; r < 4; ++r) {
      alo[r].v = *(const f16x8*)(a_g + ((size_t)h * N_SEQ + tlo * 16 + 4 * w + r) * P + quad * 8);
      ahi[r].v = *(const f16x8*)(a_g + ((size_t)h * N_SEQ + thi * 16 + 4 * w + r) * P + quad * 8);
    }

    for (int jt = 0; jt < nhi; ++jt) {
      H8 cb;
      cb.v = *(const f16x8*)(cb_g + ((size_t)h * N_SEQ + jt * 16 + m) * P + quad * 8);
      const float q0 = rowscore(ahi[0], cb, w2f, b2q, w3q);
      const float q1 = rowscore(ahi[1], cb, w2f, b2q, w3q);
      const float q2 = rowscore(ahi[2], cb, w2f, b2q, w3q);
      const float q3 = rowscore(ahi[3], cb, w2f, b2q, w3q);
      const float fh = quadreduce4(q0, q1, q2, q3, quad);
      probS[16 + 4 * w + quad][jt * 16 + m] = __float2half(fh);
      if (jt < nlo) {
        const float s0 = rowscore(alo[0], cb, w2f, b2q, w3q);
        const float s1 = rowscore(alo[1], cb, w2f, b2q, w3q);
        const float s2 = rowscore(alo[2], cb, w2f, b2q, w3q);
        const float s3 = rowscore(alo[3], cb, w2f, b2q, w3q);
        const float fl = quadreduce4(s0, s1, s2, s3, quad);
        probS[4 * w + quad][jt * 16 + m] = __float2half(fl);
      }
    }
  }
  __syncthreads();

  // ---- phase 2: per-row softmax; store UNNORMALIZED exp, inv in invS ----
  {
    const int lr = 8 * w + (lane >> 3);     // local row 0..31
    const int c  = lane & 7;                // 8 lanes per row
    const int gi = (lr < 16) ? (tlo * 16 + lr) : (thi * 16 + (lr - 16));
    float mx = -1e30f;
#pragma unroll
    for (int k = 0; k < 8; ++k) {
      const int c0 = k * 64 + c * 8;
      if (c0 > gi) break;
      H8 vv; vv.v = *(const f16x8*)&probS[lr][c0];
#pragma unroll
      for (int u = 0; u < 8; ++u) {
        const float s = __half2float(vv.h2[u >> 1].data[u & 1]);
        if (c0 + u <= gi) mx = fmaxf(mx, s);
      }
    }
#pragma unroll
    for (int msk = 1; msk < 8; msk <<= 1) mx = fmaxf(mx, __shfl_xor(mx, msk));
    float sum = 0.f;
#pragma unroll
    for (int k = 0; k < 8; ++k) {
      const int c0 = k * 64 + c * 8;
      H8 vv; vv.v = *(const f16x8*)&probS[lr][c0];
      H8 o;
#pragma unroll
      for (int u = 0; u < 4; ++u) {
        float e0 = 0.f, e1 = 0.f;
        if (c0 + 2 * u <= gi) {
          e0 = __expf(__half2float(vv.h2[u].data[0]) - mx);
          if (c0 + 2 * u + 1 <= gi)
            e1 = __expf(__half2float(vv.h2[u].data[1]) - mx);
        }
        sum += e0 + e1;
        o.h2[u] = __floats2half2_rn(e0, e1);
      }
      *(f16x8*)&probS[lr][c0] = o.v;
    }
#pragma unroll
    for (int msk = 1; msk < 8; msk <<= 1) sum += __shfl_xor(sum, msk);
    if (c == 0) invS[lr] = 1.f / sum;
  }
  __syncthreads();

  // ---- phase 3: PV. wave w -> d-tile w for both i-tiles ----
  {
    const int d0 = w * 16;
    const __half* pb = vT + ((size_t)h * DH + d0 + m) * N_SEQ + quad * 8;
#pragma unroll
    for (int half = 0; half < 2; ++half) {
      const int lbase = half ? 16 : 0;
      const int tile = half ? thi : tlo;
      const int nk = half ? ((33 - p) >> 1) : ((p + 2) >> 1);
      f32x4 acc = {0.f, 0.f, 0.f, 0.f};
      for (int k = 0; k < nk; ++k) {
        const f16x8 a = *(const f16x8*)&probS[lbase + m][k * 32 + quad * 8];
        const f16x8 b = *(const f16x8*)(pb + k * 32);
        acc = __builtin_amdgcn_mfma_f32_16x16x32_f16(a, b, acc, 0, 0, 0);
      }
#pragma unroll
      for (int r = 0; r < 4; ++r) {
        const int lrow = quad * 4 + r;
        const float val = acc[r] * invS[lbase + lrow];
        attnb[(size_t)(tile * 16 + lrow) * DIM + h * DH + d0 + m] = (short)f2bf(val);
      }
    }
  }
}

// ---------------------------------------------------------------------------
// Output GEMM: out(512x1024) = attnb @ Woutb^T. 16x16 tile/wave.
// ---------------------------------------------------------------------------
__global__ __launch_bounds__(256) void gemm_out16(
    const short* __restrict__ A, const short* __restrict__ B,
    float* __restrict__ C) {
  const int wave = blockIdx.x * 4 + (threadIdx.x >> 6);
  const int tm = wave >> 6;
  const int tn = wave & 63;
  const int lane = threadIdx.x & 63;
  const int m = lane & 15, quad = lane >> 4;

  const short* pa = A + (size_t)(tm * 16 + m) * DIM + quad * 8;
  const short* pb = B + (size_t)(tn * 16 + m) * DIM + quad * 8;

  f32x4 acc = {0.f, 0.f, 0.f, 0.f};
#pragma unroll 4
  for (int k = 0; k < DIM; k += 32) {
    const bf16x8 a = *(const bf16x8*)(pa + k);
    const bf16x8 b = *(const bf16x8*)(pb + k);
    acc = __builtin_amdgcn_mfma_f32_16x16x32_bf16(a, b, acc, 0, 0, 0);
  }
#pragma unroll
  for (int r = 0; r < 4; ++r)
    C[(size_t)(tm * 16 + quad * 4 + r) * DIM + tn * 16 + m] = acc[r];
}

// ---------------------------------------------------------------------------
extern "C" void kernel_launch(void* const* d_in, const int* in_sizes, int n_in,
                              void* d_out, int out_size, void* d_ws, size_t ws_size,
                              hipStream_t stream) {
  const float* x    = (const float*)d_in[0];
  const float* Wqkv = (const float*)d_in[1];
  const float* Wout = (const float*)d_in[2];
  const float* Wq   = (const float*)d_in[3];
  const float* bq   = (const float*)d_in[4];
  const float* Wk   = (const float*)d_in[5];
  const float* bk   = (const float*)d_in[6];
  const float* W1   = (const float*)d_in[7];
  const float* b1   = (const float*)d_in[8];
  const float* W2   = (const float*)d_in[9];
  const float* b2   = (const float*)d_in[10];
  const float* W3   = (const float*)d_in[11];
  float* out = (float*)d_out;

  float*  ws     = (float*)d_ws;
  float*  ba32   = ws;                                   // 32
  float*  bc32   = ba32 + 32;                            // 32
  __half* a_buf  = (__half*)(bc32 + 32);                 // 16*512*32
  __half* cb_buf = a_buf + (size_t)HEADS * N_SEQ * P;    // 16*512*32
  __half* vT     = cb_buf + (size_t)HEADS * N_SEQ * P;   // 16*64*512
  short*  Wcomb  = (short*)(vT + (size_t)HEADS * DH * N_SEQ); // 2048*1024
  short*  xb     = Wcomb + (size_t)2048 * DIM;           // 512*1024
  short*  Woutb  = xb + (size_t)N_SEQ * DIM;             // 1024*1024
  short*  attnb  = Woutb + (size_t)DIM * DIM;            // 512*1024

  // 1) prep: weight folding + bf16 casts
  prep<<<768, 256, 0, stream>>>(Wqkv, Wq, bq, Wk, bk, W1, x, Wout,
                                Wcomb, xb, Woutb, ba32, bc32);

  // 2) main GEMM -> fp16 a / cb(+b1) / vT
  gemm_acv<<<512, 256, 0, stream>>>(xb, Wcomb, ba32, bc32, b1,
                                    a_buf, cb_buf, vT);

  // 3) fused scores + softmax + PV (mirror-balanced pairs, 1 block/CU)
  dim3 g3(16, HEADS);
  attn_fused<<<g3, 256, 0, stream>>>(a_buf, cb_buf, W2, b2, W3, vT, attnb);

  // 4) output GEMM
  gemm_out16<<<512, 256, 0, stream>>>(attnb, Woutb, out);
}